// Round 14
// baseline (944.741 us; speedup 1.0000x reference)
//
#include <hip/hip_runtime.h>
#include <hip/hip_bf16.h>

#define DEV static __device__ __forceinline__

typedef short s16x8 __attribute__((ext_vector_type(8)));
typedef float f32x4 __attribute__((ext_vector_type(4)));
typedef unsigned short u16;

constexpr int Bn = 64, Pn = 196, ENCn = 2048, EMBn = 512, DECn = 512, ATTn = 512;
constexpr int VOCABn = 10000, Sn = 20;
constexpr int GEW = 2560;   // GE row width

DEV u16 f2bf(float x) {
  union { float f; unsigned u; } v; v.f = x;
  unsigned r = v.u + 0x7fffu + ((v.u >> 16) & 1u);
  return (u16)(r >> 16);
}
DEV float bf2f(u16 b) {
  union { unsigned u; float f; } v; v.u = ((unsigned)b) << 16;
  return v.f;
}
DEV float sigm(float x) { return 1.f / (1.f + __expf(-x)); }
DEV float tanh_fast(float x) {
  float e = __expf(2.f * x);
  return 1.f - 2.f / (e + 1.f);
}

DEV s16x8 ld8(const u16* p) { return *reinterpret_cast<const s16x8*>(p); }
DEV f32x4 mfma(s16x8 a, s16x8 b, f32x4 c) {
  return __builtin_amdgcn_mfma_f32_16x16x32_bf16(a, b, c, 0, 0, 0);
}

#define GLOAD_LDS16(gsrc, ldst)                                                \
  __builtin_amdgcn_global_load_lds(                                            \
      (const __attribute__((address_space(1))) void*)(gsrc),                   \
      (__attribute__((address_space(3))) void*)(ldst), 16, 0, 0)

// ---------------- image_feat cvt + partial mean: grid (28, 64), 7 rows/block --
__global__ __launch_bounds__(256) void k_cvtfeat_part(
    const float* __restrict__ feat, u16* __restrict__ featbf,
    float* __restrict__ pavg) {
  int b = blockIdx.y, px = blockIdx.x;     // px 0..27
  int d8 = threadIdx.x * 8;
  const float* p = feat + ((size_t)b * Pn + px * 7) * ENCn + d8;
  u16* q = featbf + ((size_t)b * Pn + px * 7) * ENCn + d8;
  float acc[8] = {};
#pragma unroll
  for (int k = 0; k < 7; k++) {
    float4 v0 = *(const float4*)(p + (size_t)k * ENCn);
    float4 v1 = *(const float4*)(p + (size_t)k * ENCn + 4);
    acc[0] += v0.x; acc[1] += v0.y; acc[2] += v0.z; acc[3] += v0.w;
    acc[4] += v1.x; acc[5] += v1.y; acc[6] += v1.z; acc[7] += v1.w;
    s16x8 o;
    o[0] = (short)f2bf(v0.x); o[1] = (short)f2bf(v0.y);
    o[2] = (short)f2bf(v0.z); o[3] = (short)f2bf(v0.w);
    o[4] = (short)f2bf(v1.x); o[5] = (short)f2bf(v1.y);
    o[6] = (short)f2bf(v1.z); o[7] = (short)f2bf(v1.w);
    *(s16x8*)(q + (size_t)k * ENCn) = o;
  }
  float* pp = pavg + ((size_t)px * Bn + b) * ENCn + d8;
  *(f32x4*)pp = f32x4{acc[0], acc[1], acc[2], acc[3]};
  *(f32x4*)(pp + 4) = f32x4{acc[4], acc[5], acc[6], acc[7]};
}

// ---------------- all conversions + W_all pack + Wemb + wdecT + avg(bf16) -----
__global__ void k_cvt_all(
    const float* __restrict__ wenc, const float* __restrict__ wdec,
    u16* __restrict__ wdec_bf,
    const float* __restrict__ Wih, u16* __restrict__ Wemb,
    const float* __restrict__ Whh, u16* __restrict__ Whh_bf,
    const float* __restrict__ fcw, u16* __restrict__ fcw_bf,
    const float* __restrict__ embw, u16* __restrict__ emb_bf,
    const float* __restrict__ h0w, u16* __restrict__ h0w_bf,
    const float* __restrict__ c0w, u16* __restrict__ c0w_bf,
    u16* __restrict__ Wall, u16* __restrict__ wdecT,
    const float* __restrict__ pavg, u16* __restrict__ avgbf) {
  int gid = blockIdx.x * 256 + threadIdx.x, stride = gridDim.x * 256;
  auto run = [&](const float* __restrict__ s, u16* __restrict__ d, int n8) {
    for (int i = gid; i < n8; i += stride) {
      const float4* sp = (const float4*)(s + (size_t)i * 8);
      float4 a = sp[0], b = sp[1];
      s16x8 o;
      o[0] = (short)f2bf(a.x); o[1] = (short)f2bf(a.y);
      o[2] = (short)f2bf(a.z); o[3] = (short)f2bf(a.w);
      o[4] = (short)f2bf(b.x); o[5] = (short)f2bf(b.y);
      o[6] = (short)f2bf(b.z); o[7] = (short)f2bf(b.w);
      *(s16x8*)(d + (size_t)i * 8) = o;
    }
  };
  run(wdec, wdec_bf, 32768);     // 512*512
  run(Whh, Whh_bf, 131072);      // 2048*512
  run(fcw, fcw_bf, 640000);      // 10000*512
  run(embw, emb_bf, 640000);     // 10000*512
  run(h0w, h0w_bf, 131072);      // 512*2048
  run(c0w, c0w_bf, 131072);      // 512*2048
  // Wemb[n][k] = Wih[n][2048+k]  (the embedding block, 2048x512)
  for (int i = gid; i < 131072; i += stride) {
    int n = i >> 6, k8 = (i & 63) * 8;
    const float* src = Wih + (size_t)n * 2560 + 2048 + k8;
    float4 a = *(const float4*)src, b = *(const float4*)(src + 4);
    s16x8 o;
    o[0] = (short)f2bf(a.x); o[1] = (short)f2bf(a.y);
    o[2] = (short)f2bf(a.z); o[3] = (short)f2bf(a.w);
    o[4] = (short)f2bf(b.x); o[5] = (short)f2bf(b.y);
    o[6] = (short)f2bf(b.z); o[7] = (short)f2bf(b.w);
    *(s16x8*)(Wemb + (size_t)i * 8) = o;
  }
  // W_all[2560][2048]: rows 0..2047 = Wih[perm(c)][0:2048]; 2048.. = wenc.
  for (int i = gid; i < 655360; i += stride) {
    int row = i >> 8, k8 = (i & 255) * 8;
    const float* src = (row < 2048)
        ? Wih + (size_t)((row >> 2) + (row & 3) * 512) * 2560 + k8
        : wenc + (size_t)(row - 2048) * 2048 + k8;
    float4 a = *(const float4*)src, b = *(const float4*)(src + 4);
    s16x8 o;
    o[0] = (short)f2bf(a.x); o[1] = (short)f2bf(a.y);
    o[2] = (short)f2bf(a.z); o[3] = (short)f2bf(a.w);
    o[4] = (short)f2bf(b.x); o[5] = (short)f2bf(b.y);
    o[6] = (short)f2bf(b.z); o[7] = (short)f2bf(b.w);
    *(s16x8*)(Wall + (size_t)i * 8) = o;
  }
  // wdecT[k][n] = wdec[n][k]
  for (int i = gid; i < 262144; i += stride) {
    int n = i >> 9, k = i & 511;
    wdecT[(size_t)k * 512 + n] = f2bf(wdec[i]);
  }
  // avgbf = bf16( sum(pavg[0..27]) / 196 )
  for (int i = gid; i < 16384; i += stride) {
    int b = i >> 8, e8 = (i & 255) * 8;
    float s[8] = {};
#pragma unroll 4
    for (int px = 0; px < 28; px++) {
      const float* pp = pavg + ((size_t)px * Bn + b) * ENCn + e8;
      float4 v0 = *(const float4*)pp, v1 = *(const float4*)(pp + 4);
      s[0] += v0.x; s[1] += v0.y; s[2] += v0.z; s[3] += v0.w;
      s[4] += v1.x; s[5] += v1.y; s[6] += v1.z; s[7] += v1.w;
    }
    s16x8 o;
#pragma unroll
    for (int j = 0; j < 8; j++) o[j] = (short)f2bf(s[j] * (1.f / 196.f));
    *(s16x8*)(avgbf + (size_t)b * ENCn + e8) = o;
  }
}

// ---------------- h0 + c0 + zero decpart[1..3] --------------------------------
__global__ __launch_bounds__(256) void k_h0c0(
    const u16* __restrict__ avgbf,
    const u16* __restrict__ h0wbf, const float* __restrict__ h0b,
    const u16* __restrict__ c0wbf, const float* __restrict__ c0b,
    u16* __restrict__ h0out, float* __restrict__ c0out,
    float* __restrict__ decpart) {
  int idx = blockIdx.x * 256 + threadIdx.x;   // 16384 threads
  float* dz = decpart + (size_t)Bn * 512;     // slices 1..3 = 98304 floats
#pragma unroll
  for (int j = 0; j < 6; j++) dz[(size_t)j * 16384 + idx] = 0.f;

  int wid = threadIdx.x >> 6, lane = threadIdx.x & 63;
  int r = lane & 15, hi = lane >> 4;
  bool isC = blockIdx.x >= 32;
  int n0 = ((int)blockIdx.x & 31) * 16;
  const u16* W = (isC ? c0wbf : h0wbf) + (size_t)(n0 + r) * ENCn + hi * 8;
  const u16* ap = avgbf + (size_t)(wid * 16 + r) * ENCn + hi * 8;
  f32x4 acc = {0.f, 0.f, 0.f, 0.f};
#pragma unroll 4
  for (int k = 0; k < ENCn; k += 32) acc = mfma(ld8(ap + k), ld8(W + k), acc);
  int col = n0 + r;
  float bb = (isC ? c0b : h0b)[col];
#pragma unroll
  for (int j = 0; j < 4; j++) {
    int row = wid * 16 + hi * 4 + j;
    float v = fmaxf(acc[j] + bb, 0.f);
    if (isC) c0out[(size_t)row * DECn + col] = v;
    else     h0out[(size_t)row * DECn + col] = f2bf(v);
  }
}

// ---------------- generic skinny GEMM (initial decpart[0]) --------------------
template<typename TA, typename TW, int K>
__global__ __launch_bounds__(256) void k_lin64(
    const TA* __restrict__ A, const TW* __restrict__ W,
    const float* __restrict__ bias1, float* __restrict__ outF, size_t ldo) {
  int wid = threadIdx.x >> 6, lane = threadIdx.x & 63;
  int r = lane & 15, hi = lane >> 4;
  int n0 = blockIdx.x * 16;
  const TA* ap = A + (size_t)(wid * 16 + r) * K + hi * 8;
  const TW* wp = W + (size_t)(n0 + r) * K + hi * 8;
  f32x4 acc = {0.f, 0.f, 0.f, 0.f};
  for (int k = 0; k < K; k += 32) acc = mfma(ld8(ap + k), ld8(wp + k), acc);
  int col = n0 + r;
  float bb = bias1 ? bias1[col] : 0.f;
#pragma unroll
  for (int j = 0; j < 4; j++) {
    int row = wid * 16 + hi * 4 + j;
    outF[(size_t)row * ldo + col] = acc[j] + bb;
  }
}

// ---------------- GE projection: [12544,2560] = feat @ Wall^T (no bias) -------
// 1D grid 1960 = 8 x 245, XCD chunk swizzle (m-panel-major within chunk).
// cols 0..2047 = G (gate-interleaved), 2048..2559 = enc_proj (bias in k_step1).
__global__ __launch_bounds__(256) void k_geproj(
    const u16* __restrict__ Abf, const u16* __restrict__ Wall,
    u16* __restrict__ GE) {
  __shared__ u16 As[128][32];
  __shared__ u16 Bs[128][32];
  int lid = blockIdx.x;
  int w = (lid & 7) * 245 + (lid >> 3);   // XCD chunk (1960 % 8 == 0, bijective)
  int bx = w % 20, by = w / 20;           // panel-major: chunk = ~12 panels x 20 ncols
  int tid = threadIdx.x;
  int wid = tid >> 6, lane = tid & 63, r = lane & 15, hi = lane >> 4;
  int wm = wid >> 1, wn = wid & 1;
  int m0 = by * 128, n0 = bx * 128;
  int srow = tid >> 2, scol = (tid & 3) * 8;
  const u16* ga  = Abf  + (size_t)(m0 + srow) * ENCn + scol;
  const u16* gb1 = Wall + (size_t)(n0 + srow) * 2048 + scol;
  const u16* gb2 = Wall + (size_t)(n0 + 64 + srow) * 2048 + scol;
  u16* As1 = &As[0][0];
  u16* Bs1 = &Bs[0][0];
  f32x4 acc[4][4] = {};
  for (int k0 = 0; k0 < ENCn; k0 += 32) {
    GLOAD_LDS16(ga + k0,                      As1 + wid * 512);
    GLOAD_LDS16(ga + k0 + (size_t)64 * ENCn,  As1 + 2048 + wid * 512);
    GLOAD_LDS16(gb1 + k0,                     Bs1 + wid * 512);
    GLOAD_LDS16(gb2 + k0,                     Bs1 + 2048 + wid * 512);
    __syncthreads();
    s16x8 af[4], bfr[4];
#pragma unroll
    for (int i = 0; i < 4; i++) af[i]  = *(const s16x8*)(As1 + (wm * 64 + i * 16 + r) * 32 + hi * 8);
#pragma unroll
    for (int j = 0; j < 4; j++) bfr[j] = *(const s16x8*)(Bs1 + (wn * 64 + j * 16 + r) * 32 + hi * 8);
#pragma unroll
    for (int i = 0; i < 4; i++)
#pragma unroll
      for (int j = 0; j < 4; j++)
        acc[i][j] = mfma(af[i], bfr[j], acc[i][j]);
    __syncthreads();
  }
#pragma unroll
  for (int i = 0; i < 4; i++)
#pragma unroll
    for (int j = 0; j < 4; j++) {
      int col = n0 + wn * 64 + j * 16 + r;
#pragma unroll
      for (int q = 0; q < 4; q++) {
        int row = m0 + wm * 64 + i * 16 + hi * 4 + q;
        GE[(size_t)row * GEW + col] = f2bf(acc[i][j][q]);
      }
    }
}

// ---------------- E = emb(caps) @ Wemb^T for ALL steps: [1280,2048], K=512 ----
__global__ __launch_bounds__(256) void k_eproj(
    const u16* __restrict__ embbf, const int* __restrict__ caps,
    const u16* __restrict__ Wemb, float* __restrict__ E) {
  __shared__ u16 As[128][32];
  __shared__ u16 Bs[128][32];
  int tid = threadIdx.x;
  int wid = tid >> 6, lane = tid & 63, r = lane & 15, hi = lane >> 4;
  int wm = wid >> 1, wn = wid & 1;
  int m0 = blockIdx.y * 128, n0 = blockIdx.x * 128;
  int srow = tid >> 2, scol = (tid & 3) * 8;
  int row1 = m0 + srow, row2 = row1 + 64;
  int id1 = caps[(row1 & 63) * Sn + (row1 >> 6)];
  int id2 = caps[(row2 & 63) * Sn + (row2 >> 6)];
  const u16* ga1 = embbf + (size_t)id1 * 512 + scol;
  const u16* ga2 = embbf + (size_t)id2 * 512 + scol;
  const u16* gb1 = Wemb + (size_t)(n0 + srow) * 512 + scol;
  const u16* gb2 = Wemb + (size_t)(n0 + 64 + srow) * 512 + scol;
  u16* As1 = &As[0][0];
  u16* Bs1 = &Bs[0][0];
  f32x4 acc[4][4] = {};
  for (int k0 = 0; k0 < 512; k0 += 32) {
    GLOAD_LDS16(ga1 + k0, As1 + wid * 512);
    GLOAD_LDS16(ga2 + k0, As1 + 2048 + wid * 512);
    GLOAD_LDS16(gb1 + k0, Bs1 + wid * 512);
    GLOAD_LDS16(gb2 + k0, Bs1 + 2048 + wid * 512);
    __syncthreads();
    s16x8 af[4], bfr[4];
#pragma unroll
    for (int i = 0; i < 4; i++) af[i]  = *(const s16x8*)(As1 + (wm * 64 + i * 16 + r) * 32 + hi * 8);
#pragma unroll
    for (int j = 0; j < 4; j++) bfr[j] = *(const s16x8*)(Bs1 + (wn * 64 + j * 16 + r) * 32 + hi * 8);
#pragma unroll
    for (int i = 0; i < 4; i++)
#pragma unroll
      for (int j = 0; j < 4; j++)
        acc[i][j] = mfma(af[i], bfr[j], acc[i][j]);
    __syncthreads();
  }
#pragma unroll
  for (int i = 0; i < 4; i++)
#pragma unroll
    for (int j = 0; j < 4; j++) {
      int col = n0 + wn * 64 + j * 16 + r;
#pragma unroll
      for (int q = 0; q < 4; q++) {
        int row = m0 + wm * 64 + i * 16 + hi * 4 + q;
        E[(size_t)row * 2048 + col] = acc[i][j][q];
      }
    }
}

// ---------------- STEP K1: attn (enc bias + decp folded) + h@Whh slices -------
__global__ __launch_bounds__(256) void k_step1(
    const u16* __restrict__ GE, const float* __restrict__ decpart,
    const float* __restrict__ wdecb, const float* __restrict__ encb,
    const float* __restrict__ Vw, const float* __restrict__ Vb,
    float* __restrict__ e_s,
    const u16* __restrict__ hin, const u16* __restrict__ Whh,
    float* __restrict__ p2) {
  int bx = blockIdx.x, by = blockIdx.y;
  int wid = threadIdx.x >> 6, lane = threadIdx.x & 63;
  if (bx < 49) {
    int p = bx * 4 + wid, b = by;
    int cb = lane * 8;
    float4 eb0 = *(const float4*)(encb + cb);
    float4 eb1 = *(const float4*)(encb + cb + 4);
    float4 dv0 = *(const float4*)(wdecb + cb);
    float4 dv1 = *(const float4*)(wdecb + cb + 4);
    dv0.x += eb0.x; dv0.y += eb0.y; dv0.z += eb0.z; dv0.w += eb0.w;
    dv1.x += eb1.x; dv1.y += eb1.y; dv1.z += eb1.z; dv1.w += eb1.w;
#pragma unroll
    for (int q = 0; q < 4; q++) {
      const float* dq = decpart + ((size_t)q * Bn + b) * 512 + cb;
      float4 v0 = *(const float4*)dq, v1 = *(const float4*)(dq + 4);
      dv0.x += v0.x; dv0.y += v0.y; dv0.z += v0.z; dv0.w += v0.w;
      dv1.x += v1.x; dv1.y += v1.y; dv1.z += v1.z; dv1.w += v1.w;
    }
    float4 vv0 = *(const float4*)(Vw + cb), vv1 = *(const float4*)(Vw + cb + 4);
    s16x8 ev = *(const s16x8*)(GE + (size_t)(b * Pn + p) * GEW + 2048 + cb);
    float s = 0.f;
    s += vv0.x * tanh_fast(bf2f((u16)ev[0]) + dv0.x);
    s += vv0.y * tanh_fast(bf2f((u16)ev[1]) + dv0.y);
    s += vv0.z * tanh_fast(bf2f((u16)ev[2]) + dv0.z);
    s += vv0.w * tanh_fast(bf2f((u16)ev[3]) + dv0.w);
    s += vv1.x * tanh_fast(bf2f((u16)ev[4]) + dv1.x);
    s += vv1.y * tanh_fast(bf2f((u16)ev[5]) + dv1.y);
    s += vv1.z * tanh_fast(bf2f((u16)ev[6]) + dv1.z);
    s += vv1.w * tanh_fast(bf2f((u16)ev[7]) + dv1.w);
    for (int m = 32; m; m >>= 1) s += __shfl_xor(s, m);
    if (lane == 0) e_s[(size_t)b * Pn + p] = s + Vb[0];
  } else {
    int sb = (bx - 49) * 64 + by;          // 0..127
    int n0 = sb * 16;
    int r = lane & 15, hi = lane >> 4;
    int brow = wid * 16 + r;
    f32x4 acc = {0.f, 0.f, 0.f, 0.f};
    const u16* a2 = hin + (size_t)brow * DECn + hi * 8;
    const u16* w2 = Whh + (size_t)(n0 + r) * 512 + hi * 8;
#pragma unroll 4
    for (int k = 0; k < 512; k += 32) acc = mfma(ld8(a2 + k), ld8(w2 + k), acc);
#pragma unroll
    for (int j = 0; j < 4; j++) {
      int row = wid * 16 + hi * 4 + j;
      p2[(size_t)row * 2048 + n0 + r] = acc[j];
    }
  }
}

// ---------------- STEP K2: softmax + GE-sum + LSTM + decp partials, 512 thr ---
__global__ __launch_bounds__(512) void k_step2(
    const float* __restrict__ e_s, const u16* __restrict__ GE,
    const float* __restrict__ p2, const float* __restrict__ Et,
    const float* __restrict__ bih, const float* __restrict__ bhh,
    float* __restrict__ cbuf, u16* __restrict__ hnew,
    const u16* __restrict__ wdecT, float* __restrict__ decpart) {
  __shared__ float sw[Pn];
  __shared__ float red[512];
  __shared__ float pacc[8 * 512];
  __shared__ float hsh[128];
  int b = blockIdx.y, c = blockIdx.x, tid = threadIdx.x;
  // softmax over 196
  float ev = (tid < Pn) ? e_s[(size_t)b * Pn + tid] : -3.0e38f;
  red[tid] = ev; __syncthreads();
  for (int s = 256; s > 0; s >>= 1) { if (tid < s) red[tid] = fmaxf(red[tid], red[tid + s]); __syncthreads(); }
  float m = red[0]; __syncthreads();
  float ex = (tid < Pn) ? __expf(ev - m) : 0.f;
  red[tid] = ex; __syncthreads();
  for (int s = 256; s > 0; s >>= 1) { if (tid < s) red[tid] += red[tid + s]; __syncthreads(); }
  float inv = 1.f / red[0];
  if (tid < Pn) sw[tid] = ex * inv;
  __syncthreads();
  // weighted sum over GE G-cols: 8 p-groups x 64 threads; thread owns 8 cols
  int g = tid >> 6, t64 = tid & 63;
  int dloc = t64 * 8;
  const u16* gp = GE + (size_t)(b * Pn) * GEW + c * 512 + dloc;
  float acc[8] = {};
#pragma unroll 2
  for (int p = g; p < Pn; p += 8) {
    float w = sw[p];
    s16x8 v = *(const s16x8*)(gp + (size_t)p * GEW);
#pragma unroll
    for (int j = 0; j < 8; j++) acc[j] += w * bf2f((u16)v[j]);
  }
#pragma unroll
  for (int j = 0; j < 8; j++) pacc[g * 512 + j * 64 + t64] = acc[j];
  __syncthreads();
  // LSTM pointwise for 128 dims (G cols interleaved lc = d_local*4+g)
  if (tid < 128) {
    int d = c * 128 + tid;
    float gv[4];
#pragma unroll
    for (int gg = 0; gg < 4; gg++) {
      int lc = tid * 4 + gg;
      int ia = (lc & 7) * 64 + (lc >> 3);
      float s = 0.f;
#pragma unroll
      for (int gr = 0; gr < 8; gr++) s += pacc[gr * 512 + ia];
      int col = gg * 512 + d;
      gv[gg] = s + p2[(size_t)b * 2048 + col] + Et[(size_t)b * 2048 + col]
             + bih[col] + bhh[col];
    }
    size_t ci = (size_t)b * DECn + d;
    float cn = sigm(gv[1]) * cbuf[ci] + sigm(gv[0]) * tanh_fast(gv[2]);
    float hn = sigm(gv[3]) * tanh_fast(cn);
    cbuf[ci] = cn;
    hnew[ci] = f2bf(hn);
    hsh[tid] = hn;
  }
  __syncthreads();
  // decp partial: this block's 128 h dims x 512 cols; thread owns 1 col
  float a0 = 0.f;
#pragma unroll 8
  for (int k = 0; k < 128; k++)
    a0 += hsh[k] * bf2f(wdecT[(size_t)(c * 128 + k) * 512 + tid]);
  decpart[((size_t)c * Bn + b) * 512 + tid] = a0;
}

// ---------------- deferred logits GEMM, bijective XCD swizzle (n-major) -------
__global__ __launch_bounds__(256) void k_logits(
    const u16* __restrict__ hA, const u16* __restrict__ Wbf,
    const float* __restrict__ bias, float* __restrict__ out) {
  __shared__ u16 As[128][32];
  __shared__ u16 Bs[128][32];
  // 790 blocks: q=98, r=6 -> bijective chunked swizzle; decode n-major
  int lid = blockIdx.x;
  int xcd = lid & 7, idx = lid >> 3;
  int w = (xcd < 6) ? xcd * 99 + idx : 6 * 99 + (xcd - 6) * 98 + idx;
  int bx = w / 10, by = w % 10;   // n-major: W slice L2-resident per XCD
  int tid = threadIdx.x;
  int wid = tid >> 6, lane = tid & 63, r = lane & 15, hi = lane >> 4;
  int wm = wid >> 1, wn = wid & 1;
  int m0 = by * 128, n0 = bx * 128;
  int srow = tid >> 2, scol = (tid & 3) * 8;
  const u16* ga = hA + (size_t)(m0 + srow) * 512 + scol;
  int br1 = n0 + srow;       if (br1 > VOCABn - 1) br1 = VOCABn - 1;
  int br2 = n0 + 64 + srow;  if (br2 > VOCABn - 1) br2 = VOCABn - 1;
  const u16* gb1 = Wbf + (size_t)br1 * 512 + scol;
  const u16* gb2 = Wbf + (size_t)br2 * 512 + scol;
  u16* As1 = &As[0][0];
  u16* Bs1 = &Bs[0][0];
  f32x4 acc[4][4] = {};
  for (int k0 = 0; k0 < 512; k0 += 32) {
    GLOAD_LDS16(ga + k0,                     As1 + wid * 512);
    GLOAD_LDS16(ga + k0 + (size_t)64 * 512,  As1 + 2048 + wid * 512);
    GLOAD_LDS16(gb1 + k0,                    Bs1 + wid * 512);
    GLOAD_LDS16(gb2 + k0,                    Bs1 + 2048 + wid * 512);
    __syncthreads();
    s16x8 af[4], bfr[4];
#pragma unroll
    for (int i = 0; i < 4; i++) af[i]  = *(const s16x8*)(As1 + (wm * 64 + i * 16 + r) * 32 + hi * 8);
#pragma unroll
    for (int j = 0; j < 4; j++) bfr[j] = *(const s16x8*)(Bs1 + (wn * 64 + j * 16 + r) * 32 + hi * 8);
#pragma unroll
    for (int i = 0; i < 4; i++)
#pragma unroll
      for (int j = 0; j < 4; j++)
        acc[i][j] = mfma(af[i], bfr[j], acc[i][j]);
    __syncthreads();
  }
#pragma unroll
  for (int i = 0; i < 4; i++)
#pragma unroll
    for (int j = 0; j < 4; j++) {
      int col = n0 + wn * 64 + j * 16 + r;
      if (col < VOCABn) {
        float bb = bias[col];
#pragma unroll
        for (int q = 0; q < 4; q++) {
          int row = m0 + wm * 64 + i * 16 + hi * 4 + q;   // row = t*64 + b
          int tt = row >> 6, b = row & 63;
          out[((size_t)b * Sn + tt) * VOCABn + col] = acc[i][j][q] + bb;
        }
      }
    }
}

// ============================================================================
extern "C" void kernel_launch(void* const* d_in, const int* in_sizes, int n_in,
                              void* d_out, int out_size, void* d_ws, size_t ws_size,
                              hipStream_t stream) {
  const float* image_feat = (const float*)d_in[0];
  const int*   captions   = (const int*)d_in[1];
  const float* wenc_w = (const float*)d_in[2];
  const float* wenc_b = (const float*)d_in[3];
  const float* wdec_w = (const float*)d_in[4];
  const float* wdec_b = (const float*)d_in[5];
  const float* V_w    = (const float*)d_in[6];
  const float* V_b    = (const float*)d_in[7];
  const float* embed_w = (const float*)d_in[8];
  const float* h0_w = (const float*)d_in[9];
  const float* h0_b = (const float*)d_in[10];
  const float* c0_w = (const float*)d_in[11];
  const float* c0_b = (const float*)d_in[12];
  const float* W_ih = (const float*)d_in[13];
  const float* b_ih = (const float*)d_in[14];
  const float* W_hh = (const float*)d_in[15];
  const float* b_hh = (const float*)d_in[16];
  const float* fc_w = (const float*)d_in[17];
  const float* fc_b = (const float*)d_in[18];
  float* out = (float*)d_out;

  char* w = (char*)d_ws;
  auto alloc = [&](size_t bytes) { void* p = (void*)w; w += (bytes + 255) & ~(size_t)255; return p; };
  u16* if_bf   = (u16*)alloc(sizeof(u16) * (size_t)Bn * Pn * ENCn);
  u16* GEbuf   = (u16*)alloc(sizeof(u16) * (size_t)Bn * Pn * GEW);
  u16* Wall    = (u16*)alloc(sizeof(u16) * (size_t)2560 * 2048);
  u16* wdec_bf = (u16*)alloc(sizeof(u16) * (size_t)ATTn * DECn);
  u16* wdecT   = (u16*)alloc(sizeof(u16) * (size_t)DECn * DECn);
  u16* Wemb    = (u16*)alloc(sizeof(u16) * (size_t)2048 * 512);
  u16* Whh_bf  = (u16*)alloc(sizeof(u16) * (size_t)2048 * 512);
  u16* fcw_bf  = (u16*)alloc(sizeof(u16) * (size_t)VOCABn * DECn);
  u16* emb_bf  = (u16*)alloc(sizeof(u16) * (size_t)VOCABn * EMBn);
  u16* h0w_bf  = (u16*)alloc(sizeof(u16) * (size_t)DECn * ENCn);
  u16* c0w_bf  = (u16*)alloc(sizeof(u16) * (size_t)DECn * ENCn);
  u16* avg_bf  = (u16*)alloc(sizeof(u16) * (size_t)Bn * ENCn);
  u16* hall    = (u16*)alloc(sizeof(u16) * (size_t)(Sn + 1) * Bn * DECn);
  float* Ebuf  = (float*)alloc(sizeof(float) * (size_t)Sn * Bn * 2048);
  float* pavg  = (float*)alloc(sizeof(float) * (size_t)28 * Bn * ENCn);
  float* e_s   = (float*)alloc(sizeof(float) * (size_t)Bn * Pn);
  float* cbuf  = (float*)alloc(sizeof(float) * (size_t)Bn * DECn);
  float* p2    = (float*)alloc(sizeof(float) * (size_t)Bn * 2048);
  float* decpart = (float*)alloc(sizeof(float) * (size_t)4 * Bn * 512);

  // one-time prep
  k_cvtfeat_part<<<dim3(28, Bn), 256, 0, stream>>>(image_feat, if_bf, pavg);
  k_cvt_all<<<2048, 256, 0, stream>>>(wenc_w, wdec_w, wdec_bf,
                                      W_ih, Wemb, W_hh, Whh_bf,
                                      fc_w, fcw_bf, embed_w, emb_bf,
                                      h0_w, h0w_bf, c0_w, c0w_bf,
                                      Wall, wdecT, pavg, avg_bf);
  k_geproj<<<1960, 256, 0, stream>>>(if_bf, Wall, GEbuf);
  k_eproj<<<dim3(16, 10), 256, 0, stream>>>(emb_bf, captions, Wemb, Ebuf);
  k_h0c0<<<64, 256, 0, stream>>>(avg_bf, h0w_bf, h0_b, c0w_bf, c0_b,
                                 hall, cbuf, decpart);
  k_lin64<u16, u16, 512><<<32, 256, 0, stream>>>(hall, wdec_bf, nullptr, decpart, 512);

  for (int t = 0; t < Sn; t++) {
    const u16* hin = hall + (size_t)t * Bn * DECn;
    u16* hnew = hall + (size_t)(t + 1) * Bn * DECn;
    k_step1<<<dim3(51, Bn), 256, 0, stream>>>(GEbuf, decpart, wdec_b, wenc_b,
                                              V_w, V_b, e_s, hin, Whh_bf, p2);
    k_step2<<<dim3(4, Bn), 512, 0, stream>>>(e_s, GEbuf, p2,
                                             Ebuf + (size_t)t * Bn * 2048,
                                             b_ih, b_hh, cbuf, hnew, wdecT, decpart);
  }
  k_logits<<<790, 256, 0, stream>>>(hall + (size_t)Bn * DECn, fcw_bf, fc_b, out);
}

// Round 15
// 942.002 us; speedup vs baseline: 1.0029x; 1.0029x over previous
//
#include <hip/hip_runtime.h>
#include <hip/hip_bf16.h>

#define DEV static __device__ __forceinline__

typedef short s16x8 __attribute__((ext_vector_type(8)));
typedef float f32x4 __attribute__((ext_vector_type(4)));
typedef unsigned short u16;

constexpr int Bn = 64, Pn = 196, ENCn = 2048, EMBn = 512, DECn = 512, ATTn = 512;
constexpr int VOCABn = 10000, Sn = 20;

DEV u16 f2bf(float x) {
  union { float f; unsigned u; } v; v.f = x;
  unsigned r = v.u + 0x7fffu + ((v.u >> 16) & 1u);
  return (u16)(r >> 16);
}
DEV float bf2f(u16 b) {
  union { unsigned u; float f; } v; v.u = ((unsigned)b) << 16;
  return v.f;
}
DEV float sigm(float x) { return 1.f / (1.f + __expf(-x)); }
DEV float tanh_fast(float x) {
  float e = __expf(2.f * x);
  return 1.f - 2.f / (e + 1.f);
}

DEV s16x8 ld8(const u16* p) { return *reinterpret_cast<const s16x8*>(p); }
DEV f32x4 mfma(s16x8 a, s16x8 b, f32x4 c) {
  return __builtin_amdgcn_mfma_f32_16x16x32_bf16(a, b, c, 0, 0, 0);
}

#define GLOAD_LDS16(gsrc, ldst)                                                \
  __builtin_amdgcn_global_load_lds(                                            \
      (const __attribute__((address_space(1))) void*)(gsrc),                   \
      (__attribute__((address_space(3))) void*)(ldst), 16, 0, 0)

// ---------------- image_feat cvt + partial mean: grid (28, 64), 7 rows/block --
__global__ __launch_bounds__(256) void k_cvtfeat_part(
    const float* __restrict__ feat, u16* __restrict__ featbf,
    float* __restrict__ pavg) {
  int b = blockIdx.y, px = blockIdx.x;     // px 0..27
  int d8 = threadIdx.x * 8;
  const float* p = feat + ((size_t)b * Pn + px * 7) * ENCn + d8;
  u16* q = featbf + ((size_t)b * Pn + px * 7) * ENCn + d8;
  float acc[8] = {};
#pragma unroll
  for (int k = 0; k < 7; k++) {
    float4 v0 = *(const float4*)(p + (size_t)k * ENCn);
    float4 v1 = *(const float4*)(p + (size_t)k * ENCn + 4);
    acc[0] += v0.x; acc[1] += v0.y; acc[2] += v0.z; acc[3] += v0.w;
    acc[4] += v1.x; acc[5] += v1.y; acc[6] += v1.z; acc[7] += v1.w;
    s16x8 o;
    o[0] = (short)f2bf(v0.x); o[1] = (short)f2bf(v0.y);
    o[2] = (short)f2bf(v0.z); o[3] = (short)f2bf(v0.w);
    o[4] = (short)f2bf(v1.x); o[5] = (short)f2bf(v1.y);
    o[6] = (short)f2bf(v1.z); o[7] = (short)f2bf(v1.w);
    *(s16x8*)(q + (size_t)k * ENCn) = o;
  }
  float* pp = pavg + ((size_t)px * Bn + b) * ENCn + d8;
  *(f32x4*)pp = f32x4{acc[0], acc[1], acc[2], acc[3]};
  *(f32x4*)(pp + 4) = f32x4{acc[4], acc[5], acc[6], acc[7]};
}

// ---------------- all conversions + W_all pack + Wemb + wdecT + avg(bf16) -----
__global__ void k_cvt_all(
    const float* __restrict__ wenc, const float* __restrict__ wdec,
    u16* __restrict__ wdec_bf,
    const float* __restrict__ Wih, u16* __restrict__ Wemb,
    const float* __restrict__ Whh, u16* __restrict__ Whh_bf,
    const float* __restrict__ fcw, u16* __restrict__ fcw_bf,
    const float* __restrict__ embw, u16* __restrict__ emb_bf,
    const float* __restrict__ h0w, u16* __restrict__ h0w_bf,
    const float* __restrict__ c0w, u16* __restrict__ c0w_bf,
    u16* __restrict__ Wall, u16* __restrict__ wdecT,
    const float* __restrict__ pavg, u16* __restrict__ avgbf) {
  int gid = blockIdx.x * 256 + threadIdx.x, stride = gridDim.x * 256;
  auto run = [&](const float* __restrict__ s, u16* __restrict__ d, int n8) {
    for (int i = gid; i < n8; i += stride) {
      const float4* sp = (const float4*)(s + (size_t)i * 8);
      float4 a = sp[0], b = sp[1];
      s16x8 o;
      o[0] = (short)f2bf(a.x); o[1] = (short)f2bf(a.y);
      o[2] = (short)f2bf(a.z); o[3] = (short)f2bf(a.w);
      o[4] = (short)f2bf(b.x); o[5] = (short)f2bf(b.y);
      o[6] = (short)f2bf(b.z); o[7] = (short)f2bf(b.w);
      *(s16x8*)(d + (size_t)i * 8) = o;
    }
  };
  run(wdec, wdec_bf, 32768);     // 512*512
  run(Whh, Whh_bf, 131072);      // 2048*512
  run(fcw, fcw_bf, 640000);      // 10000*512
  run(embw, emb_bf, 640000);     // 10000*512
  run(h0w, h0w_bf, 131072);      // 512*2048
  run(c0w, c0w_bf, 131072);      // 512*2048
  // Wemb[n][k] = Wih[n][2048+k]
  for (int i = gid; i < 131072; i += stride) {
    int n = i >> 6, k8 = (i & 63) * 8;
    const float* src = Wih + (size_t)n * 2560 + 2048 + k8;
    float4 a = *(const float4*)src, b = *(const float4*)(src + 4);
    s16x8 o;
    o[0] = (short)f2bf(a.x); o[1] = (short)f2bf(a.y);
    o[2] = (short)f2bf(a.z); o[3] = (short)f2bf(a.w);
    o[4] = (short)f2bf(b.x); o[5] = (short)f2bf(b.y);
    o[6] = (short)f2bf(b.z); o[7] = (short)f2bf(b.w);
    *(s16x8*)(Wemb + (size_t)i * 8) = o;
  }
  // W_all[2560][2048]: rows 0..2047 = Wih[perm(c)][0:2048]; 2048.. = wenc.
  for (int i = gid; i < 655360; i += stride) {
    int row = i >> 8, k8 = (i & 255) * 8;
    const float* src = (row < 2048)
        ? Wih + (size_t)((row >> 2) + (row & 3) * 512) * 2560 + k8
        : wenc + (size_t)(row - 2048) * 2048 + k8;
    float4 a = *(const float4*)src, b = *(const float4*)(src + 4);
    s16x8 o;
    o[0] = (short)f2bf(a.x); o[1] = (short)f2bf(a.y);
    o[2] = (short)f2bf(a.z); o[3] = (short)f2bf(a.w);
    o[4] = (short)f2bf(b.x); o[5] = (short)f2bf(b.y);
    o[6] = (short)f2bf(b.z); o[7] = (short)f2bf(b.w);
    *(s16x8*)(Wall + (size_t)i * 8) = o;
  }
  // wdecT[k][n] = wdec[n][k]
  for (int i = gid; i < 262144; i += stride) {
    int n = i >> 9, k = i & 511;
    wdecT[(size_t)k * 512 + n] = f2bf(wdec[i]);
  }
  // avgbf = bf16( sum(pavg[0..27]) / 196 )
  for (int i = gid; i < 16384; i += stride) {
    int b = i >> 8, e8 = (i & 255) * 8;
    float s[8] = {};
#pragma unroll 4
    for (int px = 0; px < 28; px++) {
      const float* pp = pavg + ((size_t)px * Bn + b) * ENCn + e8;
      float4 v0 = *(const float4*)pp, v1 = *(const float4*)(pp + 4);
      s[0] += v0.x; s[1] += v0.y; s[2] += v0.z; s[3] += v0.w;
      s[4] += v1.x; s[5] += v1.y; s[6] += v1.z; s[7] += v1.w;
    }
    s16x8 o;
#pragma unroll
    for (int j = 0; j < 8; j++) o[j] = (short)f2bf(s[j] * (1.f / 196.f));
    *(s16x8*)(avgbf + (size_t)b * ENCn + e8) = o;
  }
}

// ---------------- h0 + c0 + zero decpart[1..3] --------------------------------
__global__ __launch_bounds__(256) void k_h0c0(
    const u16* __restrict__ avgbf,
    const u16* __restrict__ h0wbf, const float* __restrict__ h0b,
    const u16* __restrict__ c0wbf, const float* __restrict__ c0b,
    u16* __restrict__ h0out, float* __restrict__ c0out,
    float* __restrict__ decpart) {
  int idx = blockIdx.x * 256 + threadIdx.x;   // 16384 threads
  float* dz = decpart + (size_t)Bn * 512;     // slices 1..3 = 98304 floats
#pragma unroll
  for (int j = 0; j < 6; j++) dz[(size_t)j * 16384 + idx] = 0.f;

  int wid = threadIdx.x >> 6, lane = threadIdx.x & 63;
  int r = lane & 15, hi = lane >> 4;
  bool isC = blockIdx.x >= 32;
  int n0 = ((int)blockIdx.x & 31) * 16;
  const u16* W = (isC ? c0wbf : h0wbf) + (size_t)(n0 + r) * ENCn + hi * 8;
  const u16* ap = avgbf + (size_t)(wid * 16 + r) * ENCn + hi * 8;
  f32x4 acc = {0.f, 0.f, 0.f, 0.f};
#pragma unroll 4
  for (int k = 0; k < ENCn; k += 32) acc = mfma(ld8(ap + k), ld8(W + k), acc);
  int col = n0 + r;
  float bb = (isC ? c0b : h0b)[col];
#pragma unroll
  for (int j = 0; j < 4; j++) {
    int row = wid * 16 + hi * 4 + j;
    float v = fmaxf(acc[j] + bb, 0.f);
    if (isC) c0out[(size_t)row * DECn + col] = v;
    else     h0out[(size_t)row * DECn + col] = f2bf(v);
  }
}

// ---------------- generic skinny GEMM (initial decpart[0]) --------------------
template<typename TA, typename TW, int K>
__global__ __launch_bounds__(256) void k_lin64(
    const TA* __restrict__ A, const TW* __restrict__ W,
    const float* __restrict__ bias1, float* __restrict__ outF, size_t ldo) {
  int wid = threadIdx.x >> 6, lane = threadIdx.x & 63;
  int r = lane & 15, hi = lane >> 4;
  int n0 = blockIdx.x * 16;
  const TA* ap = A + (size_t)(wid * 16 + r) * K + hi * 8;
  const TW* wp = W + (size_t)(n0 + r) * K + hi * 8;
  f32x4 acc = {0.f, 0.f, 0.f, 0.f};
  for (int k = 0; k < K; k += 32) acc = mfma(ld8(ap + k), ld8(wp + k), acc);
  int col = n0 + r;
  float bb = bias1 ? bias1[col] : 0.f;
#pragma unroll
  for (int j = 0; j < 4; j++) {
    int row = wid * 16 + hi * 4 + j;
    outF[(size_t)row * ldo + col] = acc[j] + bb;
  }
}

// ---------------- merged GE projection, COMPACT outputs -----------------------
// [12544,2560] = feat @ Wall^T. 1D grid 1960 = 8x245, XCD chunk swizzle.
// bx<16 -> G[row][col] (2048-wide, gate-interleaved); bx>=16 -> encp[row][col']
// (512-wide compact, bias folded into k_step1). Output select is BLOCK-UNIFORM.
__global__ __launch_bounds__(256) void k_geproj(
    const u16* __restrict__ Abf, const u16* __restrict__ Wall,
    u16* __restrict__ G, u16* __restrict__ encp) {
  __shared__ u16 As[128][32];
  __shared__ u16 Bs[128][32];
  int lid = blockIdx.x;
  int w = (lid & 7) * 245 + (lid >> 3);   // XCD chunk (bijective, 1960%8==0)
  int bx = w % 20, by = w / 20;           // panel-major within chunk
  int tid = threadIdx.x;
  int wid = tid >> 6, lane = tid & 63, r = lane & 15, hi = lane >> 4;
  int wm = wid >> 1, wn = wid & 1;
  int m0 = by * 128, n0 = bx * 128;
  int srow = tid >> 2, scol = (tid & 3) * 8;
  const u16* ga  = Abf  + (size_t)(m0 + srow) * ENCn + scol;
  const u16* gb1 = Wall + (size_t)(n0 + srow) * 2048 + scol;
  const u16* gb2 = Wall + (size_t)(n0 + 64 + srow) * 2048 + scol;
  // block-uniform output select (computed once, no per-element branch)
  u16* outp; int ostride, ocol0;
  if (bx < 16) { outp = G;    ostride = 2048; ocol0 = n0; }
  else         { outp = encp; ostride = 512;  ocol0 = n0 - 2048; }
  u16* As1 = &As[0][0];
  u16* Bs1 = &Bs[0][0];
  f32x4 acc[4][4] = {};
  for (int k0 = 0; k0 < ENCn; k0 += 32) {
    GLOAD_LDS16(ga + k0,                      As1 + wid * 512);
    GLOAD_LDS16(ga + k0 + (size_t)64 * ENCn,  As1 + 2048 + wid * 512);
    GLOAD_LDS16(gb1 + k0,                     Bs1 + wid * 512);
    GLOAD_LDS16(gb2 + k0,                     Bs1 + 2048 + wid * 512);
    __syncthreads();
    s16x8 af[4], bfr[4];
#pragma unroll
    for (int i = 0; i < 4; i++) af[i]  = *(const s16x8*)(As1 + (wm * 64 + i * 16 + r) * 32 + hi * 8);
#pragma unroll
    for (int j = 0; j < 4; j++) bfr[j] = *(const s16x8*)(Bs1 + (wn * 64 + j * 16 + r) * 32 + hi * 8);
#pragma unroll
    for (int i = 0; i < 4; i++)
#pragma unroll
      for (int j = 0; j < 4; j++)
        acc[i][j] = mfma(af[i], bfr[j], acc[i][j]);
    __syncthreads();
  }
#pragma unroll
  for (int i = 0; i < 4; i++)
#pragma unroll
    for (int j = 0; j < 4; j++) {
      int col = ocol0 + wn * 64 + j * 16 + r;
#pragma unroll
      for (int q = 0; q < 4; q++) {
        int row = m0 + wm * 64 + i * 16 + hi * 4 + q;
        outp[(size_t)row * ostride + col] = f2bf(acc[i][j][q]);
      }
    }
}

// ---------------- E = emb(caps) @ Wemb^T for ALL steps: [1280,2048], K=512 ----
__global__ __launch_bounds__(256) void k_eproj(
    const u16* __restrict__ embbf, const int* __restrict__ caps,
    const u16* __restrict__ Wemb, float* __restrict__ E) {
  __shared__ u16 As[128][32];
  __shared__ u16 Bs[128][32];
  int tid = threadIdx.x;
  int wid = tid >> 6, lane = tid & 63, r = lane & 15, hi = lane >> 4;
  int wm = wid >> 1, wn = wid & 1;
  int m0 = blockIdx.y * 128, n0 = blockIdx.x * 128;
  int srow = tid >> 2, scol = (tid & 3) * 8;
  int row1 = m0 + srow, row2 = row1 + 64;
  int id1 = caps[(row1 & 63) * Sn + (row1 >> 6)];
  int id2 = caps[(row2 & 63) * Sn + (row2 >> 6)];
  const u16* ga1 = embbf + (size_t)id1 * 512 + scol;
  const u16* ga2 = embbf + (size_t)id2 * 512 + scol;
  const u16* gb1 = Wemb + (size_t)(n0 + srow) * 512 + scol;
  const u16* gb2 = Wemb + (size_t)(n0 + 64 + srow) * 512 + scol;
  u16* As1 = &As[0][0];
  u16* Bs1 = &Bs[0][0];
  f32x4 acc[4][4] = {};
  for (int k0 = 0; k0 < 512; k0 += 32) {
    GLOAD_LDS16(ga1 + k0, As1 + wid * 512);
    GLOAD_LDS16(ga2 + k0, As1 + 2048 + wid * 512);
    GLOAD_LDS16(gb1 + k0, Bs1 + wid * 512);
    GLOAD_LDS16(gb2 + k0, Bs1 + 2048 + wid * 512);
    __syncthreads();
    s16x8 af[4], bfr[4];
#pragma unroll
    for (int i = 0; i < 4; i++) af[i]  = *(const s16x8*)(As1 + (wm * 64 + i * 16 + r) * 32 + hi * 8);
#pragma unroll
    for (int j = 0; j < 4; j++) bfr[j] = *(const s16x8*)(Bs1 + (wn * 64 + j * 16 + r) * 32 + hi * 8);
#pragma unroll
    for (int i = 0; i < 4; i++)
#pragma unroll
      for (int j = 0; j < 4; j++)
        acc[i][j] = mfma(af[i], bfr[j], acc[i][j]);
    __syncthreads();
  }
#pragma unroll
  for (int i = 0; i < 4; i++)
#pragma unroll
    for (int j = 0; j < 4; j++) {
      int col = n0 + wn * 64 + j * 16 + r;
#pragma unroll
      for (int q = 0; q < 4; q++) {
        int row = m0 + wm * 64 + i * 16 + hi * 4 + q;
        E[(size_t)row * 2048 + col] = acc[i][j][q];
      }
    }
}

// ---------------- STEP K1: attn (enc bias + decp folded) + h@Whh slices -------
__global__ __launch_bounds__(256) void k_step1(
    const u16* __restrict__ encp, const float* __restrict__ decpart,
    const float* __restrict__ wdecb, const float* __restrict__ encb,
    const float* __restrict__ Vw, const float* __restrict__ Vb,
    float* __restrict__ e_s,
    const u16* __restrict__ hin, const u16* __restrict__ Whh,
    float* __restrict__ p2) {
  int bx = blockIdx.x, by = blockIdx.y;
  int wid = threadIdx.x >> 6, lane = threadIdx.x & 63;
  if (bx < 49) {
    int p = bx * 4 + wid, b = by;
    int cb = lane * 8;
    float4 eb0 = *(const float4*)(encb + cb);
    float4 eb1 = *(const float4*)(encb + cb + 4);
    float4 dv0 = *(const float4*)(wdecb + cb);
    float4 dv1 = *(const float4*)(wdecb + cb + 4);
    dv0.x += eb0.x; dv0.y += eb0.y; dv0.z += eb0.z; dv0.w += eb0.w;
    dv1.x += eb1.x; dv1.y += eb1.y; dv1.z += eb1.z; dv1.w += eb1.w;
#pragma unroll
    for (int q = 0; q < 4; q++) {
      const float* dq = decpart + ((size_t)q * Bn + b) * 512 + cb;
      float4 v0 = *(const float4*)dq, v1 = *(const float4*)(dq + 4);
      dv0.x += v0.x; dv0.y += v0.y; dv0.z += v0.z; dv0.w += v0.w;
      dv1.x += v1.x; dv1.y += v1.y; dv1.z += v1.z; dv1.w += v1.w;
    }
    float4 vv0 = *(const float4*)(Vw + cb), vv1 = *(const float4*)(Vw + cb + 4);
    s16x8 ev = *(const s16x8*)(encp + (((size_t)(b * Pn + p)) << 9) + cb);
    float s = 0.f;
    s += vv0.x * tanh_fast(bf2f((u16)ev[0]) + dv0.x);
    s += vv0.y * tanh_fast(bf2f((u16)ev[1]) + dv0.y);
    s += vv0.z * tanh_fast(bf2f((u16)ev[2]) + dv0.z);
    s += vv0.w * tanh_fast(bf2f((u16)ev[3]) + dv0.w);
    s += vv1.x * tanh_fast(bf2f((u16)ev[4]) + dv1.x);
    s += vv1.y * tanh_fast(bf2f((u16)ev[5]) + dv1.y);
    s += vv1.z * tanh_fast(bf2f((u16)ev[6]) + dv1.z);
    s += vv1.w * tanh_fast(bf2f((u16)ev[7]) + dv1.w);
    for (int m = 32; m; m >>= 1) s += __shfl_xor(s, m);
    if (lane == 0) e_s[(size_t)b * Pn + p] = s + Vb[0];
  } else {
    int sb = (bx - 49) * 64 + by;          // 0..127
    int n0 = sb * 16;
    int r = lane & 15, hi = lane >> 4;
    int brow = wid * 16 + r;
    f32x4 acc = {0.f, 0.f, 0.f, 0.f};
    const u16* a2 = hin + (size_t)brow * DECn + hi * 8;
    const u16* w2 = Whh + (size_t)(n0 + r) * 512 + hi * 8;
#pragma unroll 4
    for (int k = 0; k < 512; k += 32) acc = mfma(ld8(a2 + k), ld8(w2 + k), acc);
#pragma unroll
    for (int j = 0; j < 4; j++) {
      int row = wid * 16 + hi * 4 + j;
      p2[(size_t)row * 2048 + n0 + r] = acc[j];
    }
  }
}

// ---------------- STEP K2: softmax + G-sum + LSTM + decp partials, 512 thr ----
__global__ __launch_bounds__(512) void k_step2(
    const float* __restrict__ e_s, const u16* __restrict__ G,
    const float* __restrict__ p2, const float* __restrict__ Et,
    const float* __restrict__ bih, const float* __restrict__ bhh,
    float* __restrict__ cbuf, u16* __restrict__ hnew,
    const u16* __restrict__ wdecT, float* __restrict__ decpart) {
  __shared__ float sw[Pn];
  __shared__ float red[512];
  __shared__ float pacc[8 * 512];
  __shared__ float hsh[128];
  int b = blockIdx.y, c = blockIdx.x, tid = threadIdx.x;
  // softmax over 196
  float ev = (tid < Pn) ? e_s[(size_t)b * Pn + tid] : -3.0e38f;
  red[tid] = ev; __syncthreads();
  for (int s = 256; s > 0; s >>= 1) { if (tid < s) red[tid] = fmaxf(red[tid], red[tid + s]); __syncthreads(); }
  float m = red[0]; __syncthreads();
  float ex = (tid < Pn) ? __expf(ev - m) : 0.f;
  red[tid] = ex; __syncthreads();
  for (int s = 256; s > 0; s >>= 1) { if (tid < s) red[tid] += red[tid + s]; __syncthreads(); }
  float inv = 1.f / red[0];
  if (tid < Pn) sw[tid] = ex * inv;
  __syncthreads();
  // weighted sum: 8 p-groups x 64 threads; thread owns 8 cols
  int g = tid >> 6, t64 = tid & 63;
  int dloc = t64 * 8;
  const u16* gp = G + (size_t)b * Pn * 2048 + c * 512 + dloc;
  float acc[8] = {};
#pragma unroll 2
  for (int p = g; p < Pn; p += 8) {
    float w = sw[p];
    s16x8 v = *(const s16x8*)(gp + (size_t)p * 2048);
#pragma unroll
    for (int j = 0; j < 8; j++) acc[j] += w * bf2f((u16)v[j]);
  }
#pragma unroll
  for (int j = 0; j < 8; j++) pacc[g * 512 + j * 64 + t64] = acc[j];
  __syncthreads();
  // LSTM pointwise for 128 dims (G cols interleaved lc = d_local*4+g)
  if (tid < 128) {
    int d = c * 128 + tid;
    float gv[4];
#pragma unroll
    for (int gg = 0; gg < 4; gg++) {
      int lc = tid * 4 + gg;
      int ia = (lc & 7) * 64 + (lc >> 3);
      float s = 0.f;
#pragma unroll
      for (int gr = 0; gr < 8; gr++) s += pacc[gr * 512 + ia];
      int col = gg * 512 + d;
      gv[gg] = s + p2[(size_t)b * 2048 + col] + Et[(size_t)b * 2048 + col]
             + bih[col] + bhh[col];
    }
    size_t ci = (size_t)b * DECn + d;
    float cn = sigm(gv[1]) * cbuf[ci] + sigm(gv[0]) * tanh_fast(gv[2]);
    float hn = sigm(gv[3]) * tanh_fast(cn);
    cbuf[ci] = cn;
    hnew[ci] = f2bf(hn);
    hsh[tid] = hn;
  }
  __syncthreads();
  // decp partial: this block's 128 h dims x 512 cols; thread owns 1 col
  float a0 = 0.f;
#pragma unroll 8
  for (int k = 0; k < 128; k++)
    a0 += hsh[k] * bf2f(wdecT[(size_t)(c * 128 + k) * 512 + tid]);
  decpart[((size_t)c * Bn + b) * 512 + tid] = a0;
}

// ---------------- deferred logits GEMM, bijective XCD swizzle (n-major) -------
__global__ __launch_bounds__(256) void k_logits(
    const u16* __restrict__ hA, const u16* __restrict__ Wbf,
    const float* __restrict__ bias, float* __restrict__ out) {
  __shared__ u16 As[128][32];
  __shared__ u16 Bs[128][32];
  int lid = blockIdx.x;
  int xcd = lid & 7, idx = lid >> 3;
  int w = (xcd < 6) ? xcd * 99 + idx : 6 * 99 + (xcd - 6) * 98 + idx;
  int bx = w / 10, by = w % 10;   // n-major: W slice L2-resident per XCD
  int tid = threadIdx.x;
  int wid = tid >> 6, lane = tid & 63, r = lane & 15, hi = lane >> 4;
  int wm = wid >> 1, wn = wid & 1;
  int m0 = by * 128, n0 = bx * 128;
  int srow = tid >> 2, scol = (tid & 3) * 8;
  const u16* ga = hA + (size_t)(m0 + srow) * 512 + scol;
  int br1 = n0 + srow;       if (br1 > VOCABn - 1) br1 = VOCABn - 1;
  int br2 = n0 + 64 + srow;  if (br2 > VOCABn - 1) br2 = VOCABn - 1;
  const u16* gb1 = Wbf + (size_t)br1 * 512 + scol;
  const u16* gb2 = Wbf + (size_t)br2 * 512 + scol;
  u16* As1 = &As[0][0];
  u16* Bs1 = &Bs[0][0];
  f32x4 acc[4][4] = {};
  for (int k0 = 0; k0 < 512; k0 += 32) {
    GLOAD_LDS16(ga + k0,                     As1 + wid * 512);
    GLOAD_LDS16(ga + k0 + (size_t)64 * 512,  As1 + 2048 + wid * 512);
    GLOAD_LDS16(gb1 + k0,                    Bs1 + wid * 512);
    GLOAD_LDS16(gb2 + k0,                    Bs1 + 2048 + wid * 512);
    __syncthreads();
    s16x8 af[4], bfr[4];
#pragma unroll
    for (int i = 0; i < 4; i++) af[i]  = *(const s16x8*)(As1 + (wm * 64 + i * 16 + r) * 32 + hi * 8);
#pragma unroll
    for (int j = 0; j < 4; j++) bfr[j] = *(const s16x8*)(Bs1 + (wn * 64 + j * 16 + r) * 32 + hi * 8);
#pragma unroll
    for (int i = 0; i < 4; i++)
#pragma unroll
      for (int j = 0; j < 4; j++)
        acc[i][j] = mfma(af[i], bfr[j], acc[i][j]);
    __syncthreads();
  }
#pragma unroll
  for (int i = 0; i < 4; i++)
#pragma unroll
    for (int j = 0; j < 4; j++) {
      int col = n0 + wn * 64 + j * 16 + r;
      if (col < VOCABn) {
        float bb = bias[col];
#pragma unroll
        for (int q = 0; q < 4; q++) {
          int row = m0 + wm * 64 + i * 16 + hi * 4 + q;   // row = t*64 + b
          int tt = row >> 6, b = row & 63;
          out[((size_t)b * Sn + tt) * VOCABn + col] = acc[i][j][q] + bb;
        }
      }
    }
}

// ============================================================================
extern "C" void kernel_launch(void* const* d_in, const int* in_sizes, int n_in,
                              void* d_out, int out_size, void* d_ws, size_t ws_size,
                              hipStream_t stream) {
  const float* image_feat = (const float*)d_in[0];
  const int*   captions   = (const int*)d_in[1];
  const float* wenc_w = (const float*)d_in[2];
  const float* wenc_b = (const float*)d_in[3];
  const float* wdec_w = (const float*)d_in[4];
  const float* wdec_b = (const float*)d_in[5];
  const float* V_w    = (const float*)d_in[6];
  const float* V_b    = (const float*)d_in[7];
  const float* embed_w = (const float*)d_in[8];
  const float* h0_w = (const float*)d_in[9];
  const float* h0_b = (const float*)d_in[10];
  const float* c0_w = (const float*)d_in[11];
  const float* c0_b = (const float*)d_in[12];
  const float* W_ih = (const float*)d_in[13];
  const float* b_ih = (const float*)d_in[14];
  const float* W_hh = (const float*)d_in[15];
  const float* b_hh = (const float*)d_in[16];
  const float* fc_w = (const float*)d_in[17];
  const float* fc_b = (const float*)d_in[18];
  float* out = (float*)d_out;

  char* w = (char*)d_ws;
  auto alloc = [&](size_t bytes) { void* p = (void*)w; w += (bytes + 255) & ~(size_t)255; return p; };
  u16* if_bf   = (u16*)alloc(sizeof(u16) * (size_t)Bn * Pn * ENCn);
  u16* Gbuf    = (u16*)alloc(sizeof(u16) * (size_t)Bn * Pn * 2048);
  u16* encp    = (u16*)alloc(sizeof(u16) * (size_t)Bn * Pn * ATTn);
  u16* Wall    = (u16*)alloc(sizeof(u16) * (size_t)2560 * 2048);
  u16* wdec_bf = (u16*)alloc(sizeof(u16) * (size_t)ATTn * DECn);
  u16* wdecT   = (u16*)alloc(sizeof(u16) * (size_t)DECn * DECn);
  u16* Wemb    = (u16*)alloc(sizeof(u16) * (size_t)2048 * 512);
  u16* Whh_bf  = (u16*)alloc(sizeof(u16) * (size_t)2048 * 512);
  u16* fcw_bf  = (u16*)alloc(sizeof(u16) * (size_t)VOCABn * DECn);
  u16* emb_bf  = (u16*)alloc(sizeof(u16) * (size_t)VOCABn * EMBn);
  u16* h0w_bf  = (u16*)alloc(sizeof(u16) * (size_t)DECn * ENCn);
  u16* c0w_bf  = (u16*)alloc(sizeof(u16) * (size_t)DECn * ENCn);
  u16* avg_bf  = (u16*)alloc(sizeof(u16) * (size_t)Bn * ENCn);
  u16* hall    = (u16*)alloc(sizeof(u16) * (size_t)(Sn + 1) * Bn * DECn);
  float* Ebuf  = (float*)alloc(sizeof(float) * (size_t)Sn * Bn * 2048);
  float* pavg  = (float*)alloc(sizeof(float) * (size_t)28 * Bn * ENCn);
  float* e_s   = (float*)alloc(sizeof(float) * (size_t)Bn * Pn);
  float* cbuf  = (float*)alloc(sizeof(float) * (size_t)Bn * DECn);
  float* p2    = (float*)alloc(sizeof(float) * (size_t)Bn * 2048);
  float* decpart = (float*)alloc(sizeof(float) * (size_t)4 * Bn * 512);

  // one-time prep
  k_cvtfeat_part<<<dim3(28, Bn), 256, 0, stream>>>(image_feat, if_bf, pavg);
  k_cvt_all<<<2048, 256, 0, stream>>>(wenc_w, wdec_w, wdec_bf,
                                      W_ih, Wemb, W_hh, Whh_bf,
                                      fc_w, fcw_bf, embed_w, emb_bf,
                                      h0_w, h0w_bf, c0_w, c0w_bf,
                                      Wall, wdecT, pavg, avg_bf);
  k_geproj<<<1960, 256, 0, stream>>>(if_bf, Wall, Gbuf, encp);
  k_eproj<<<dim3(16, 10), 256, 0, stream>>>(emb_bf, captions, Wemb, Ebuf);
  k_h0c0<<<64, 256, 0, stream>>>(avg_bf, h0w_bf, h0_b, c0w_bf, c0_b,
                                 hall, cbuf, decpart);
  k_lin64<u16, u16, 512><<<32, 256, 0, stream>>>(hall, wdec_bf, nullptr, decpart, 512);

  for (int t = 0; t < Sn; t++) {
    const u16* hin = hall + (size_t)t * Bn * DECn;
    u16* hnew = hall + (size_t)(t + 1) * Bn * DECn;
    k_step1<<<dim3(51, Bn), 256, 0, stream>>>(encp, decpart, wdec_b, wenc_b,
                                              V_w, V_b, e_s, hin, Whh_bf, p2);
    k_step2<<<dim3(4, Bn), 512, 0, stream>>>(e_s, Gbuf, p2,
                                             Ebuf + (size_t)t * Bn * 2048,
                                             b_ih, b_hh, cbuf, hnew, wdecT, decpart);
  }
  k_logits<<<790, 256, 0, stream>>>(hall + (size_t)Bn * DECn, fcw_bf, fc_b, out);
}

// Round 16
// 932.998 us; speedup vs baseline: 1.0126x; 1.0097x over previous
//
#include <hip/hip_runtime.h>
#include <hip/hip_bf16.h>

#define DEV static __device__ __forceinline__

typedef short s16x8 __attribute__((ext_vector_type(8)));
typedef float f32x4 __attribute__((ext_vector_type(4)));
typedef unsigned short u16;

constexpr int Bn = 64, Pn = 196, ENCn = 2048, EMBn = 512, DECn = 512, ATTn = 512;
constexpr int VOCABn = 10000, Sn = 20;

DEV u16 f2bf(float x) {
  union { float f; unsigned u; } v; v.f = x;
  unsigned r = v.u + 0x7fffu + ((v.u >> 16) & 1u);
  return (u16)(r >> 16);
}
DEV float bf2f(u16 b) {
  union { unsigned u; float f; } v; v.u = ((unsigned)b) << 16;
  return v.f;
}
DEV float sigm(float x) { return 1.f / (1.f + __expf(-x)); }
DEV float tanh_fast(float x) {
  float e = __expf(2.f * x);
  return 1.f - 2.f / (e + 1.f);
}

DEV s16x8 ld8(const u16* p) { return *reinterpret_cast<const s16x8*>(p); }
DEV f32x4 mfma(s16x8 a, s16x8 b, f32x4 c) {
  return __builtin_amdgcn_mfma_f32_16x16x32_bf16(a, b, c, 0, 0, 0);
}

#define GLOAD_LDS16(gsrc, ldst)                                                \
  __builtin_amdgcn_global_load_lds(                                            \
      (const __attribute__((address_space(1))) void*)(gsrc),                   \
      (__attribute__((address_space(3))) void*)(ldst), 16, 0, 0)

// ---------------- image_feat cvt + partial mean: grid (28, 64), 7 rows/block --
__global__ __launch_bounds__(256) void k_cvtfeat_part(
    const float* __restrict__ feat, u16* __restrict__ featbf,
    float* __restrict__ pavg) {
  int b = blockIdx.y, px = blockIdx.x;     // px 0..27
  int d8 = threadIdx.x * 8;
  const float* p = feat + ((size_t)b * Pn + px * 7) * ENCn + d8;
  u16* q = featbf + ((size_t)b * Pn + px * 7) * ENCn + d8;
  float acc[8] = {};
#pragma unroll
  for (int k = 0; k < 7; k++) {
    float4 v0 = *(const float4*)(p + (size_t)k * ENCn);
    float4 v1 = *(const float4*)(p + (size_t)k * ENCn + 4);
    acc[0] += v0.x; acc[1] += v0.y; acc[2] += v0.z; acc[3] += v0.w;
    acc[4] += v1.x; acc[5] += v1.y; acc[6] += v1.z; acc[7] += v1.w;
    s16x8 o;
    o[0] = (short)f2bf(v0.x); o[1] = (short)f2bf(v0.y);
    o[2] = (short)f2bf(v0.z); o[3] = (short)f2bf(v0.w);
    o[4] = (short)f2bf(v1.x); o[5] = (short)f2bf(v1.y);
    o[6] = (short)f2bf(v1.z); o[7] = (short)f2bf(v1.w);
    *(s16x8*)(q + (size_t)k * ENCn) = o;
  }
  float* pp = pavg + ((size_t)px * Bn + b) * ENCn + d8;
  *(f32x4*)pp = f32x4{acc[0], acc[1], acc[2], acc[3]};
  *(f32x4*)(pp + 4) = f32x4{acc[4], acc[5], acc[6], acc[7]};
}

// ---------------- all conversions + W_all pack + Wemb + wdecT + avg(bf16) -----
__global__ void k_cvt_all(
    const float* __restrict__ wenc, const float* __restrict__ wdec,
    u16* __restrict__ wdec_bf,
    const float* __restrict__ Wih, u16* __restrict__ Wemb,
    const float* __restrict__ Whh, u16* __restrict__ Whh_bf,
    const float* __restrict__ fcw, u16* __restrict__ fcw_bf,
    const float* __restrict__ embw, u16* __restrict__ emb_bf,
    const float* __restrict__ h0w, u16* __restrict__ h0w_bf,
    const float* __restrict__ c0w, u16* __restrict__ c0w_bf,
    u16* __restrict__ Wall, u16* __restrict__ wdecT,
    const float* __restrict__ pavg, u16* __restrict__ avgbf) {
  int gid = blockIdx.x * 256 + threadIdx.x, stride = gridDim.x * 256;
  auto run = [&](const float* __restrict__ s, u16* __restrict__ d, int n8) {
    for (int i = gid; i < n8; i += stride) {
      const float4* sp = (const float4*)(s + (size_t)i * 8);
      float4 a = sp[0], b = sp[1];
      s16x8 o;
      o[0] = (short)f2bf(a.x); o[1] = (short)f2bf(a.y);
      o[2] = (short)f2bf(a.z); o[3] = (short)f2bf(a.w);
      o[4] = (short)f2bf(b.x); o[5] = (short)f2bf(b.y);
      o[6] = (short)f2bf(b.z); o[7] = (short)f2bf(b.w);
      *(s16x8*)(d + (size_t)i * 8) = o;
    }
  };
  run(wdec, wdec_bf, 32768);     // 512*512
  run(Whh, Whh_bf, 131072);      // 2048*512
  run(fcw, fcw_bf, 640000);      // 10000*512
  run(embw, emb_bf, 640000);     // 10000*512
  run(h0w, h0w_bf, 131072);      // 512*2048
  run(c0w, c0w_bf, 131072);      // 512*2048
  // Wemb[n][k] = Wih[n][2048+k]
  for (int i = gid; i < 131072; i += stride) {
    int n = i >> 6, k8 = (i & 63) * 8;
    const float* src = Wih + (size_t)n * 2560 + 2048 + k8;
    float4 a = *(const float4*)src, b = *(const float4*)(src + 4);
    s16x8 o;
    o[0] = (short)f2bf(a.x); o[1] = (short)f2bf(a.y);
    o[2] = (short)f2bf(a.z); o[3] = (short)f2bf(a.w);
    o[4] = (short)f2bf(b.x); o[5] = (short)f2bf(b.y);
    o[6] = (short)f2bf(b.z); o[7] = (short)f2bf(b.w);
    *(s16x8*)(Wemb + (size_t)i * 8) = o;
  }
  // W_all[2560][2048]: rows 0..2047 = Wih[perm(c)][0:2048]; 2048.. = wenc.
  for (int i = gid; i < 655360; i += stride) {
    int row = i >> 8, k8 = (i & 255) * 8;
    const float* src = (row < 2048)
        ? Wih + (size_t)((row >> 2) + (row & 3) * 512) * 2560 + k8
        : wenc + (size_t)(row - 2048) * 2048 + k8;
    float4 a = *(const float4*)src, b = *(const float4*)(src + 4);
    s16x8 o;
    o[0] = (short)f2bf(a.x); o[1] = (short)f2bf(a.y);
    o[2] = (short)f2bf(a.z); o[3] = (short)f2bf(a.w);
    o[4] = (short)f2bf(b.x); o[5] = (short)f2bf(b.y);
    o[6] = (short)f2bf(b.z); o[7] = (short)f2bf(b.w);
    *(s16x8*)(Wall + (size_t)i * 8) = o;
  }
  // wdecT[k][n] = wdec[n][k]
  for (int i = gid; i < 262144; i += stride) {
    int n = i >> 9, k = i & 511;
    wdecT[(size_t)k * 512 + n] = f2bf(wdec[i]);
  }
  // avgbf = bf16( sum(pavg[0..27]) / 196 )
  for (int i = gid; i < 16384; i += stride) {
    int b = i >> 8, e8 = (i & 255) * 8;
    float s[8] = {};
#pragma unroll 4
    for (int px = 0; px < 28; px++) {
      const float* pp = pavg + ((size_t)px * Bn + b) * ENCn + e8;
      float4 v0 = *(const float4*)pp, v1 = *(const float4*)(pp + 4);
      s[0] += v0.x; s[1] += v0.y; s[2] += v0.z; s[3] += v0.w;
      s[4] += v1.x; s[5] += v1.y; s[6] += v1.z; s[7] += v1.w;
    }
    s16x8 o;
#pragma unroll
    for (int j = 0; j < 8; j++) o[j] = (short)f2bf(s[j] * (1.f / 196.f));
    *(s16x8*)(avgbf + (size_t)b * ENCn + e8) = o;
  }
}

// ---------------- h0 + c0 + zero decpart[1..3] --------------------------------
__global__ __launch_bounds__(256) void k_h0c0(
    const u16* __restrict__ avgbf,
    const u16* __restrict__ h0wbf, const float* __restrict__ h0b,
    const u16* __restrict__ c0wbf, const float* __restrict__ c0b,
    u16* __restrict__ h0out, float* __restrict__ c0out,
    float* __restrict__ decpart) {
  int idx = blockIdx.x * 256 + threadIdx.x;   // 16384 threads
  float* dz = decpart + (size_t)Bn * 512;     // slices 1..3 = 98304 floats
#pragma unroll
  for (int j = 0; j < 6; j++) dz[(size_t)j * 16384 + idx] = 0.f;

  int wid = threadIdx.x >> 6, lane = threadIdx.x & 63;
  int r = lane & 15, hi = lane >> 4;
  bool isC = blockIdx.x >= 32;
  int n0 = ((int)blockIdx.x & 31) * 16;
  const u16* W = (isC ? c0wbf : h0wbf) + (size_t)(n0 + r) * ENCn + hi * 8;
  const u16* ap = avgbf + (size_t)(wid * 16 + r) * ENCn + hi * 8;
  f32x4 acc = {0.f, 0.f, 0.f, 0.f};
#pragma unroll 4
  for (int k = 0; k < ENCn; k += 32) acc = mfma(ld8(ap + k), ld8(W + k), acc);
  int col = n0 + r;
  float bb = (isC ? c0b : h0b)[col];
#pragma unroll
  for (int j = 0; j < 4; j++) {
    int row = wid * 16 + hi * 4 + j;
    float v = fmaxf(acc[j] + bb, 0.f);
    if (isC) c0out[(size_t)row * DECn + col] = v;
    else     h0out[(size_t)row * DECn + col] = f2bf(v);
  }
}

// ---------------- generic skinny GEMM (initial decpart[0]) --------------------
template<typename TA, typename TW, int K>
__global__ __launch_bounds__(256) void k_lin64(
    const TA* __restrict__ A, const TW* __restrict__ W,
    const float* __restrict__ bias1, float* __restrict__ outF, size_t ldo) {
  int wid = threadIdx.x >> 6, lane = threadIdx.x & 63;
  int r = lane & 15, hi = lane >> 4;
  int n0 = blockIdx.x * 16;
  const TA* ap = A + (size_t)(wid * 16 + r) * K + hi * 8;
  const TW* wp = W + (size_t)(n0 + r) * K + hi * 8;
  f32x4 acc = {0.f, 0.f, 0.f, 0.f};
  for (int k = 0; k < K; k += 32) acc = mfma(ld8(ap + k), ld8(wp + k), acc);
  int col = n0 + r;
  float bb = bias1 ? bias1[col] : 0.f;
#pragma unroll
  for (int j = 0; j < 4; j++) {
    int row = wid * 16 + hi * 4 + j;
    outF[(size_t)row * ldo + col] = acc[j] + bb;
  }
}

// ---------------- G projection: [12544,2048] = feat @ Wall[0:2048]^T ----------
// 1D grid 1568 = 8 x 196, XCD chunk swizzle (panel-major within chunk).
__global__ __launch_bounds__(256) void k_gproj(
    const u16* __restrict__ Abf, const u16* __restrict__ Wall,
    u16* __restrict__ G) {
  __shared__ u16 As[128][32];
  __shared__ u16 Bs[128][32];
  int lid = blockIdx.x;
  int w = (lid & 7) * 196 + (lid >> 3);   // bijective (1568 % 8 == 0)
  int bx = w & 15, by = w >> 4;           // panel-major: 16 n-blocks share A panel
  int tid = threadIdx.x;
  int wid = tid >> 6, lane = tid & 63, r = lane & 15, hi = lane >> 4;
  int wm = wid >> 1, wn = wid & 1;
  int m0 = by * 128, n0 = bx * 128;
  int srow = tid >> 2, scol = (tid & 3) * 8;
  const u16* ga  = Abf  + (size_t)(m0 + srow) * ENCn + scol;
  const u16* gb1 = Wall + (size_t)(n0 + srow) * 2048 + scol;
  const u16* gb2 = Wall + (size_t)(n0 + 64 + srow) * 2048 + scol;
  u16* As1 = &As[0][0];
  u16* Bs1 = &Bs[0][0];
  f32x4 acc[4][4] = {};
  for (int k0 = 0; k0 < ENCn; k0 += 32) {
    GLOAD_LDS16(ga + k0,                      As1 + wid * 512);
    GLOAD_LDS16(ga + k0 + (size_t)64 * ENCn,  As1 + 2048 + wid * 512);
    GLOAD_LDS16(gb1 + k0,                     Bs1 + wid * 512);
    GLOAD_LDS16(gb2 + k0,                     Bs1 + 2048 + wid * 512);
    __syncthreads();
    s16x8 af[4], bfr[4];
#pragma unroll
    for (int i = 0; i < 4; i++) af[i]  = *(const s16x8*)(As1 + (wm * 64 + i * 16 + r) * 32 + hi * 8);
#pragma unroll
    for (int j = 0; j < 4; j++) bfr[j] = *(const s16x8*)(Bs1 + (wn * 64 + j * 16 + r) * 32 + hi * 8);
#pragma unroll
    for (int i = 0; i < 4; i++)
#pragma unroll
      for (int j = 0; j < 4; j++)
        acc[i][j] = mfma(af[i], bfr[j], acc[i][j]);
    __syncthreads();
  }
#pragma unroll
  for (int i = 0; i < 4; i++)
#pragma unroll
    for (int j = 0; j < 4; j++) {
      int col = n0 + wn * 64 + j * 16 + r;
#pragma unroll
      for (int q = 0; q < 4; q++) {
        int row = m0 + wm * 64 + i * 16 + hi * 4 + q;
        G[(size_t)row * 2048 + col] = f2bf(acc[i][j][q]);
      }
    }
}

// ---------------- enc projection: [12544,512] = feat @ Wall[2048:]^T + b ------
// 1D grid 392 = 8 x 49, XCD chunk swizzle.
__global__ __launch_bounds__(256) void k_encproj(
    const u16* __restrict__ Abf, const u16* __restrict__ Wall,
    const float* __restrict__ encb, u16* __restrict__ encp) {
  __shared__ u16 As[128][32];
  __shared__ u16 Bs[128][32];
  int lid = blockIdx.x;
  int w = (lid & 7) * 49 + (lid >> 3);    // bijective (392 % 8 == 0)
  int bx = w & 3, by = w >> 2;
  int tid = threadIdx.x;
  int wid = tid >> 6, lane = tid & 63, r = lane & 15, hi = lane >> 4;
  int wm = wid >> 1, wn = wid & 1;
  int m0 = by * 128, n0 = bx * 128;
  int srow = tid >> 2, scol = (tid & 3) * 8;
  const u16* ga  = Abf  + (size_t)(m0 + srow) * ENCn + scol;
  const u16* gb1 = Wall + (size_t)(2048 + n0 + srow) * 2048 + scol;
  const u16* gb2 = Wall + (size_t)(2048 + n0 + 64 + srow) * 2048 + scol;
  u16* As1 = &As[0][0];
  u16* Bs1 = &Bs[0][0];
  f32x4 acc[4][4] = {};
  for (int k0 = 0; k0 < ENCn; k0 += 32) {
    GLOAD_LDS16(ga + k0,                      As1 + wid * 512);
    GLOAD_LDS16(ga + k0 + (size_t)64 * ENCn,  As1 + 2048 + wid * 512);
    GLOAD_LDS16(gb1 + k0,                     Bs1 + wid * 512);
    GLOAD_LDS16(gb2 + k0,                     Bs1 + 2048 + wid * 512);
    __syncthreads();
    s16x8 af[4], bfr[4];
#pragma unroll
    for (int i = 0; i < 4; i++) af[i]  = *(const s16x8*)(As1 + (wm * 64 + i * 16 + r) * 32 + hi * 8);
#pragma unroll
    for (int j = 0; j < 4; j++) bfr[j] = *(const s16x8*)(Bs1 + (wn * 64 + j * 16 + r) * 32 + hi * 8);
#pragma unroll
    for (int i = 0; i < 4; i++)
#pragma unroll
      for (int j = 0; j < 4; j++)
        acc[i][j] = mfma(af[i], bfr[j], acc[i][j]);
    __syncthreads();
  }
#pragma unroll
  for (int i = 0; i < 4; i++)
#pragma unroll
    for (int j = 0; j < 4; j++) {
      int col = n0 + wn * 64 + j * 16 + r;
      float bb = encb[col];
#pragma unroll
      for (int q = 0; q < 4; q++) {
        int row = m0 + wm * 64 + i * 16 + hi * 4 + q;
        encp[(size_t)row * 512 + col] = f2bf(acc[i][j][q] + bb);
      }
    }
}

// ---------------- E = emb(caps) @ Wemb^T for ALL steps: [1280,2048], K=512 ----
__global__ __launch_bounds__(256) void k_eproj(
    const u16* __restrict__ embbf, const int* __restrict__ caps,
    const u16* __restrict__ Wemb, float* __restrict__ E) {
  __shared__ u16 As[128][32];
  __shared__ u16 Bs[128][32];
  int tid = threadIdx.x;
  int wid = tid >> 6, lane = tid & 63, r = lane & 15, hi = lane >> 4;
  int wm = wid >> 1, wn = wid & 1;
  int m0 = blockIdx.y * 128, n0 = blockIdx.x * 128;
  int srow = tid >> 2, scol = (tid & 3) * 8;
  int row1 = m0 + srow, row2 = row1 + 64;
  int id1 = caps[(row1 & 63) * Sn + (row1 >> 6)];
  int id2 = caps[(row2 & 63) * Sn + (row2 >> 6)];
  const u16* ga1 = embbf + (size_t)id1 * 512 + scol;
  const u16* ga2 = embbf + (size_t)id2 * 512 + scol;
  const u16* gb1 = Wemb + (size_t)(n0 + srow) * 512 + scol;
  const u16* gb2 = Wemb + (size_t)(n0 + 64 + srow) * 512 + scol;
  u16* As1 = &As[0][0];
  u16* Bs1 = &Bs[0][0];
  f32x4 acc[4][4] = {};
  for (int k0 = 0; k0 < 512; k0 += 32) {
    GLOAD_LDS16(ga1 + k0, As1 + wid * 512);
    GLOAD_LDS16(ga2 + k0, As1 + 2048 + wid * 512);
    GLOAD_LDS16(gb1 + k0, Bs1 + wid * 512);
    GLOAD_LDS16(gb2 + k0, Bs1 + 2048 + wid * 512);
    __syncthreads();
    s16x8 af[4], bfr[4];
#pragma unroll
    for (int i = 0; i < 4; i++) af[i]  = *(const s16x8*)(As1 + (wm * 64 + i * 16 + r) * 32 + hi * 8);
#pragma unroll
    for (int j = 0; j < 4; j++) bfr[j] = *(const s16x8*)(Bs1 + (wn * 64 + j * 16 + r) * 32 + hi * 8);
#pragma unroll
    for (int i = 0; i < 4; i++)
#pragma unroll
      for (int j = 0; j < 4; j++)
        acc[i][j] = mfma(af[i], bfr[j], acc[i][j]);
    __syncthreads();
  }
#pragma unroll
  for (int i = 0; i < 4; i++)
#pragma unroll
    for (int j = 0; j < 4; j++) {
      int col = n0 + wn * 64 + j * 16 + r;
#pragma unroll
      for (int q = 0; q < 4; q++) {
        int row = m0 + wm * 64 + i * 16 + hi * 4 + q;
        E[(size_t)row * 2048 + col] = acc[i][j][q];
      }
    }
}

// ---------------- STEP K1: attn (decp from partials) + h@Whh slices -----------
__global__ __launch_bounds__(256) void k_step1(
    const u16* __restrict__ encp, const float* __restrict__ decpart,
    const float* __restrict__ wdecb,
    const float* __restrict__ Vw, const float* __restrict__ Vb,
    float* __restrict__ e_s,
    const u16* __restrict__ hin, const u16* __restrict__ Whh,
    float* __restrict__ p2) {
  int bx = blockIdx.x, by = blockIdx.y;
  int wid = threadIdx.x >> 6, lane = threadIdx.x & 63;
  if (bx < 49) {
    int p = bx * 4 + wid, b = by;
    int cb = lane * 8;
    float4 dv0 = *(const float4*)(wdecb + cb);
    float4 dv1 = *(const float4*)(wdecb + cb + 4);
#pragma unroll
    for (int q = 0; q < 4; q++) {
      const float* dq = decpart + ((size_t)q * Bn + b) * 512 + cb;
      float4 v0 = *(const float4*)dq, v1 = *(const float4*)(dq + 4);
      dv0.x += v0.x; dv0.y += v0.y; dv0.z += v0.z; dv0.w += v0.w;
      dv1.x += v1.x; dv1.y += v1.y; dv1.z += v1.z; dv1.w += v1.w;
    }
    float4 vv0 = *(const float4*)(Vw + cb), vv1 = *(const float4*)(Vw + cb + 4);
    s16x8 ev = *(const s16x8*)(encp + (((size_t)(b * Pn + p)) << 9) + cb);
    float s = 0.f;
    s += vv0.x * tanh_fast(bf2f((u16)ev[0]) + dv0.x);
    s += vv0.y * tanh_fast(bf2f((u16)ev[1]) + dv0.y);
    s += vv0.z * tanh_fast(bf2f((u16)ev[2]) + dv0.z);
    s += vv0.w * tanh_fast(bf2f((u16)ev[3]) + dv0.w);
    s += vv1.x * tanh_fast(bf2f((u16)ev[4]) + dv1.x);
    s += vv1.y * tanh_fast(bf2f((u16)ev[5]) + dv1.y);
    s += vv1.z * tanh_fast(bf2f((u16)ev[6]) + dv1.z);
    s += vv1.w * tanh_fast(bf2f((u16)ev[7]) + dv1.w);
    for (int m = 32; m; m >>= 1) s += __shfl_xor(s, m);
    if (lane == 0) e_s[(size_t)b * Pn + p] = s + Vb[0];
  } else {
    int sb = (bx - 49) * 64 + by;          // 0..127
    int n0 = sb * 16;
    int r = lane & 15, hi = lane >> 4;
    int brow = wid * 16 + r;
    f32x4 acc = {0.f, 0.f, 0.f, 0.f};
    const u16* a2 = hin + (size_t)brow * DECn + hi * 8;
    const u16* w2 = Whh + (size_t)(n0 + r) * 512 + hi * 8;
#pragma unroll 4
    for (int k = 0; k < 512; k += 32) acc = mfma(ld8(a2 + k), ld8(w2 + k), acc);
#pragma unroll
    for (int j = 0; j < 4; j++) {
      int row = wid * 16 + hi * 4 + j;
      p2[(size_t)row * 2048 + n0 + r] = acc[j];
    }
  }
}

// ---------------- STEP K2: softmax + G-sum + LSTM + decp partials, 512 thr ----
__global__ __launch_bounds__(512) void k_step2(
    const float* __restrict__ e_s, const u16* __restrict__ G,
    const float* __restrict__ p2, const float* __restrict__ Et,
    const float* __restrict__ bih, const float* __restrict__ bhh,
    float* __restrict__ cbuf, u16* __restrict__ hnew,
    const u16* __restrict__ wdecT, float* __restrict__ decpart) {
  __shared__ float sw[Pn];
  __shared__ float red[512];
  __shared__ float pacc[8 * 512];
  __shared__ float hsh[128];
  int b = blockIdx.y, c = blockIdx.x, tid = threadIdx.x;
  // softmax over 196
  float ev = (tid < Pn) ? e_s[(size_t)b * Pn + tid] : -3.0e38f;
  red[tid] = ev; __syncthreads();
  for (int s = 256; s > 0; s >>= 1) { if (tid < s) red[tid] = fmaxf(red[tid], red[tid + s]); __syncthreads(); }
  float m = red[0]; __syncthreads();
  float ex = (tid < Pn) ? __expf(ev - m) : 0.f;
  red[tid] = ex; __syncthreads();
  for (int s = 256; s > 0; s >>= 1) { if (tid < s) red[tid] += red[tid + s]; __syncthreads(); }
  float inv = 1.f / red[0];
  if (tid < Pn) sw[tid] = ex * inv;
  __syncthreads();
  // weighted sum: 8 p-groups x 64 threads; thread owns 8 cols
  int g = tid >> 6, t64 = tid & 63;
  int dloc = t64 * 8;
  const u16* gp = G + (size_t)b * Pn * 2048 + c * 512 + dloc;
  float acc[8] = {};
#pragma unroll 2
  for (int p = g; p < Pn; p += 8) {
    float w = sw[p];
    s16x8 v = *(const s16x8*)(gp + (size_t)p * 2048);
#pragma unroll
    for (int j = 0; j < 8; j++) acc[j] += w * bf2f((u16)v[j]);
  }
#pragma unroll
  for (int j = 0; j < 8; j++) pacc[g * 512 + j * 64 + t64] = acc[j];
  __syncthreads();
  // LSTM pointwise for 128 dims (G cols interleaved lc = d_local*4+g)
  if (tid < 128) {
    int d = c * 128 + tid;
    float gv[4];
#pragma unroll
    for (int gg = 0; gg < 4; gg++) {
      int lc = tid * 4 + gg;
      int ia = (lc & 7) * 64 + (lc >> 3);
      float s = 0.f;
#pragma unroll
      for (int gr = 0; gr < 8; gr++) s += pacc[gr * 512 + ia];
      int col = gg * 512 + d;
      gv[gg] = s + p2[(size_t)b * 2048 + col] + Et[(size_t)b * 2048 + col]
             + bih[col] + bhh[col];
    }
    size_t ci = (size_t)b * DECn + d;
    float cn = sigm(gv[1]) * cbuf[ci] + sigm(gv[0]) * tanh_fast(gv[2]);
    float hn = sigm(gv[3]) * tanh_fast(cn);
    cbuf[ci] = cn;
    hnew[ci] = f2bf(hn);
    hsh[tid] = hn;
  }
  __syncthreads();
  // decp partial: this block's 128 h dims x 512 cols; thread owns 1 col
  float a0 = 0.f;
#pragma unroll 8
  for (int k = 0; k < 128; k++)
    a0 += hsh[k] * bf2f(wdecT[(size_t)(c * 128 + k) * 512 + tid]);
  decpart[((size_t)c * Bn + b) * 512 + tid] = a0;
}

// ---------------- deferred logits GEMM, bijective XCD swizzle (n-major) -------
__global__ __launch_bounds__(256) void k_logits(
    const u16* __restrict__ hA, const u16* __restrict__ Wbf,
    const float* __restrict__ bias, float* __restrict__ out) {
  __shared__ u16 As[128][32];
  __shared__ u16 Bs[128][32];
  int lid = blockIdx.x;
  int xcd = lid & 7, idx = lid >> 3;
  int w = (xcd < 6) ? xcd * 99 + idx : 6 * 99 + (xcd - 6) * 98 + idx;
  int bx = w / 10, by = w % 10;   // n-major: W slice L2-resident per XCD
  int tid = threadIdx.x;
  int wid = tid >> 6, lane = tid & 63, r = lane & 15, hi = lane >> 4;
  int wm = wid >> 1, wn = wid & 1;
  int m0 = by * 128, n0 = bx * 128;
  int srow = tid >> 2, scol = (tid & 3) * 8;
  const u16* ga = hA + (size_t)(m0 + srow) * 512 + scol;
  int br1 = n0 + srow;       if (br1 > VOCABn - 1) br1 = VOCABn - 1;
  int br2 = n0 + 64 + srow;  if (br2 > VOCABn - 1) br2 = VOCABn - 1;
  const u16* gb1 = Wbf + (size_t)br1 * 512 + scol;
  const u16* gb2 = Wbf + (size_t)br2 * 512 + scol;
  u16* As1 = &As[0][0];
  u16* Bs1 = &Bs[0][0];
  f32x4 acc[4][4] = {};
  for (int k0 = 0; k0 < 512; k0 += 32) {
    GLOAD_LDS16(ga + k0,                     As1 + wid * 512);
    GLOAD_LDS16(ga + k0 + (size_t)64 * 512,  As1 + 2048 + wid * 512);
    GLOAD_LDS16(gb1 + k0,                    Bs1 + wid * 512);
    GLOAD_LDS16(gb2 + k0,                    Bs1 + 2048 + wid * 512);
    __syncthreads();
    s16x8 af[4], bfr[4];
#pragma unroll
    for (int i = 0; i < 4; i++) af[i]  = *(const s16x8*)(As1 + (wm * 64 + i * 16 + r) * 32 + hi * 8);
#pragma unroll
    for (int j = 0; j < 4; j++) bfr[j] = *(const s16x8*)(Bs1 + (wn * 64 + j * 16 + r) * 32 + hi * 8);
#pragma unroll
    for (int i = 0; i < 4; i++)
#pragma unroll
      for (int j = 0; j < 4; j++)
        acc[i][j] = mfma(af[i], bfr[j], acc[i][j]);
    __syncthreads();
  }
#pragma unroll
  for (int i = 0; i < 4; i++)
#pragma unroll
    for (int j = 0; j < 4; j++) {
      int col = n0 + wn * 64 + j * 16 + r;
      if (col < VOCABn) {
        float bb = bias[col];
#pragma unroll
        for (int q = 0; q < 4; q++) {
          int row = m0 + wm * 64 + i * 16 + hi * 4 + q;   // row = t*64 + b
          int tt = row >> 6, b = row & 63;
          out[((size_t)b * Sn + tt) * VOCABn + col] = acc[i][j][q] + bb;
        }
      }
    }
}

// ============================================================================
extern "C" void kernel_launch(void* const* d_in, const int* in_sizes, int n_in,
                              void* d_out, int out_size, void* d_ws, size_t ws_size,
                              hipStream_t stream) {
  const float* image_feat = (const float*)d_in[0];
  const int*   captions   = (const int*)d_in[1];
  const float* wenc_w = (const float*)d_in[2];
  const float* wenc_b = (const float*)d_in[3];
  const float* wdec_w = (const float*)d_in[4];
  const float* wdec_b = (const float*)d_in[5];
  const float* V_w    = (const float*)d_in[6];
  const float* V_b    = (const float*)d_in[7];
  const float* embed_w = (const float*)d_in[8];
  const float* h0_w = (const float*)d_in[9];
  const float* h0_b = (const float*)d_in[10];
  const float* c0_w = (const float*)d_in[11];
  const float* c0_b = (const float*)d_in[12];
  const float* W_ih = (const float*)d_in[13];
  const float* b_ih = (const float*)d_in[14];
  const float* W_hh = (const float*)d_in[15];
  const float* b_hh = (const float*)d_in[16];
  const float* fc_w = (const float*)d_in[17];
  const float* fc_b = (const float*)d_in[18];
  float* out = (float*)d_out;

  char* w = (char*)d_ws;
  auto alloc = [&](size_t bytes) { void* p = (void*)w; w += (bytes + 255) & ~(size_t)255; return p; };
  u16* if_bf   = (u16*)alloc(sizeof(u16) * (size_t)Bn * Pn * ENCn);
  u16* Gbuf    = (u16*)alloc(sizeof(u16) * (size_t)Bn * Pn * 2048);
  u16* encp    = (u16*)alloc(sizeof(u16) * (size_t)Bn * Pn * ATTn);
  u16* Wall    = (u16*)alloc(sizeof(u16) * (size_t)2560 * 2048);
  u16* wdec_bf = (u16*)alloc(sizeof(u16) * (size_t)ATTn * DECn);
  u16* wdecT   = (u16*)alloc(sizeof(u16) * (size_t)DECn * DECn);
  u16* Wemb    = (u16*)alloc(sizeof(u16) * (size_t)2048 * 512);
  u16* Whh_bf  = (u16*)alloc(sizeof(u16) * (size_t)2048 * 512);
  u16* fcw_bf  = (u16*)alloc(sizeof(u16) * (size_t)VOCABn * DECn);
  u16* emb_bf  = (u16*)alloc(sizeof(u16) * (size_t)VOCABn * EMBn);
  u16* h0w_bf  = (u16*)alloc(sizeof(u16) * (size_t)DECn * ENCn);
  u16* c0w_bf  = (u16*)alloc(sizeof(u16) * (size_t)DECn * ENCn);
  u16* avg_bf  = (u16*)alloc(sizeof(u16) * (size_t)Bn * ENCn);
  u16* hall    = (u16*)alloc(sizeof(u16) * (size_t)(Sn + 1) * Bn * DECn);
  float* Ebuf  = (float*)alloc(sizeof(float) * (size_t)Sn * Bn * 2048);
  float* pavg  = (float*)alloc(sizeof(float) * (size_t)28 * Bn * ENCn);
  float* e_s   = (float*)alloc(sizeof(float) * (size_t)Bn * Pn);
  float* cbuf  = (float*)alloc(sizeof(float) * (size_t)Bn * DECn);
  float* p2    = (float*)alloc(sizeof(float) * (size_t)Bn * 2048);
  float* decpart = (float*)alloc(sizeof(float) * (size_t)4 * Bn * 512);

  // one-time prep
  k_cvtfeat_part<<<dim3(28, Bn), 256, 0, stream>>>(image_feat, if_bf, pavg);
  k_cvt_all<<<2048, 256, 0, stream>>>(wenc_w, wdec_w, wdec_bf,
                                      W_ih, Wemb, W_hh, Whh_bf,
                                      fc_w, fcw_bf, embed_w, emb_bf,
                                      h0_w, h0w_bf, c0_w, c0w_bf,
                                      Wall, wdecT, pavg, avg_bf);
  k_gproj<<<1568, 256, 0, stream>>>(if_bf, Wall, Gbuf);
  k_encproj<<<392, 256, 0, stream>>>(if_bf, Wall, wenc_b, encp);
  k_eproj<<<dim3(16, 10), 256, 0, stream>>>(emb_bf, captions, Wemb, Ebuf);
  k_h0c0<<<64, 256, 0, stream>>>(avg_bf, h0w_bf, h0_b, c0w_bf, c0_b,
                                 hall, cbuf, decpart);
  k_lin64<u16, u16, 512><<<32, 256, 0, stream>>>(hall, wdec_bf, nullptr, decpart, 512);

  for (int t = 0; t < Sn; t++) {
    const u16* hin = hall + (size_t)t * Bn * DECn;
    u16* hnew = hall + (size_t)(t + 1) * Bn * DECn;
    k_step1<<<dim3(51, Bn), 256, 0, stream>>>(encp, decpart, wdec_b, V_w, V_b, e_s,
                                              hin, Whh_bf, p2);
    k_step2<<<dim3(4, Bn), 512, 0, stream>>>(e_s, Gbuf, p2,
                                             Ebuf + (size_t)t * Bn * 2048,
                                             b_ih, b_hh, cbuf, hnew, wdecT, decpart);
  }
  k_logits<<<790, 256, 0, stream>>>(hall + (size_t)Bn * DECn, fcw_bf, fc_b, out);
}

// Round 17
// 930.048 us; speedup vs baseline: 1.0158x; 1.0032x over previous
//
#include <hip/hip_runtime.h>
#include <hip/hip_bf16.h>

#define DEV static __device__ __forceinline__

typedef short s16x8 __attribute__((ext_vector_type(8)));
typedef float f32x4 __attribute__((ext_vector_type(4)));
typedef unsigned short u16;

constexpr int Bn = 64, Pn = 196, ENCn = 2048, EMBn = 512, DECn = 512, ATTn = 512;
constexpr int VOCABn = 10000, Sn = 20;

DEV u16 f2bf(float x) {
  union { float f; unsigned u; } v; v.f = x;
  unsigned r = v.u + 0x7fffu + ((v.u >> 16) & 1u);
  return (u16)(r >> 16);
}
DEV float bf2f(u16 b) {
  union { unsigned u; float f; } v; v.u = ((unsigned)b) << 16;
  return v.f;
}
DEV float sigm(float x) { return 1.f / (1.f + __expf(-x)); }
DEV float tanh_fast(float x) {
  float e = __expf(2.f * x);
  return 1.f - 2.f / (e + 1.f);
}

DEV s16x8 ld8(const u16* p) { return *reinterpret_cast<const s16x8*>(p); }
DEV f32x4 mfma(s16x8 a, s16x8 b, f32x4 c) {
  return __builtin_amdgcn_mfma_f32_16x16x32_bf16(a, b, c, 0, 0, 0);
}

#define GLOAD_LDS16(gsrc, ldst)                                                \
  __builtin_amdgcn_global_load_lds(                                            \
      (const __attribute__((address_space(1))) void*)(gsrc),                   \
      (__attribute__((address_space(3))) void*)(ldst), 16, 0, 0)

// ---------------- image_feat cvt + partial mean: grid (28, 64), 7 rows/block --
__global__ __launch_bounds__(256) void k_cvtfeat_part(
    const float* __restrict__ feat, u16* __restrict__ featbf,
    float* __restrict__ pavg) {
  int b = blockIdx.y, px = blockIdx.x;     // px 0..27
  int d8 = threadIdx.x * 8;
  const float* p = feat + ((size_t)b * Pn + px * 7) * ENCn + d8;
  u16* q = featbf + ((size_t)b * Pn + px * 7) * ENCn + d8;
  float acc[8] = {};
#pragma unroll
  for (int k = 0; k < 7; k++) {
    float4 v0 = *(const float4*)(p + (size_t)k * ENCn);
    float4 v1 = *(const float4*)(p + (size_t)k * ENCn + 4);
    acc[0] += v0.x; acc[1] += v0.y; acc[2] += v0.z; acc[3] += v0.w;
    acc[4] += v1.x; acc[5] += v1.y; acc[6] += v1.z; acc[7] += v1.w;
    s16x8 o;
    o[0] = (short)f2bf(v0.x); o[1] = (short)f2bf(v0.y);
    o[2] = (short)f2bf(v0.z); o[3] = (short)f2bf(v0.w);
    o[4] = (short)f2bf(v1.x); o[5] = (short)f2bf(v1.y);
    o[6] = (short)f2bf(v1.z); o[7] = (short)f2bf(v1.w);
    *(s16x8*)(q + (size_t)k * ENCn) = o;
  }
  float* pp = pavg + ((size_t)px * Bn + b) * ENCn + d8;
  *(f32x4*)pp = f32x4{acc[0], acc[1], acc[2], acc[3]};
  *(f32x4*)(pp + 4) = f32x4{acc[4], acc[5], acc[6], acc[7]};
}

// ---------------- all conversions + W_all pack + Wemb + wdecT + avg(bf16) -----
__global__ void k_cvt_all(
    const float* __restrict__ wenc, const float* __restrict__ wdec,
    u16* __restrict__ wdec_bf,
    const float* __restrict__ Wih, u16* __restrict__ Wemb,
    const float* __restrict__ Whh, u16* __restrict__ Whh_bf,
    const float* __restrict__ fcw, u16* __restrict__ fcw_bf,
    const float* __restrict__ embw, u16* __restrict__ emb_bf,
    const float* __restrict__ h0w, u16* __restrict__ h0w_bf,
    const float* __restrict__ c0w, u16* __restrict__ c0w_bf,
    u16* __restrict__ Wall, u16* __restrict__ wdecT,
    const float* __restrict__ pavg, u16* __restrict__ avgbf) {
  int gid = blockIdx.x * 256 + threadIdx.x, stride = gridDim.x * 256;
  auto run = [&](const float* __restrict__ s, u16* __restrict__ d, int n8) {
    for (int i = gid; i < n8; i += stride) {
      const float4* sp = (const float4*)(s + (size_t)i * 8);
      float4 a = sp[0], b = sp[1];
      s16x8 o;
      o[0] = (short)f2bf(a.x); o[1] = (short)f2bf(a.y);
      o[2] = (short)f2bf(a.z); o[3] = (short)f2bf(a.w);
      o[4] = (short)f2bf(b.x); o[5] = (short)f2bf(b.y);
      o[6] = (short)f2bf(b.z); o[7] = (short)f2bf(b.w);
      *(s16x8*)(d + (size_t)i * 8) = o;
    }
  };
  run(wdec, wdec_bf, 32768);     // 512*512
  run(Whh, Whh_bf, 131072);      // 2048*512
  run(fcw, fcw_bf, 640000);      // 10000*512
  run(embw, emb_bf, 640000);     // 10000*512
  run(h0w, h0w_bf, 131072);      // 512*2048
  run(c0w, c0w_bf, 131072);      // 512*2048
  // Wemb[n][k] = Wih[n][2048+k]
  for (int i = gid; i < 131072; i += stride) {
    int n = i >> 6, k8 = (i & 63) * 8;
    const float* src = Wih + (size_t)n * 2560 + 2048 + k8;
    float4 a = *(const float4*)src, b = *(const float4*)(src + 4);
    s16x8 o;
    o[0] = (short)f2bf(a.x); o[1] = (short)f2bf(a.y);
    o[2] = (short)f2bf(a.z); o[3] = (short)f2bf(a.w);
    o[4] = (short)f2bf(b.x); o[5] = (short)f2bf(b.y);
    o[6] = (short)f2bf(b.z); o[7] = (short)f2bf(b.w);
    *(s16x8*)(Wemb + (size_t)i * 8) = o;
  }
  // W_all[2560][2048]: rows 0..2047 = Wih[perm(c)][0:2048]; 2048.. = wenc.
  for (int i = gid; i < 655360; i += stride) {
    int row = i >> 8, k8 = (i & 255) * 8;
    const float* src = (row < 2048)
        ? Wih + (size_t)((row >> 2) + (row & 3) * 512) * 2560 + k8
        : wenc + (size_t)(row - 2048) * 2048 + k8;
    float4 a = *(const float4*)src, b = *(const float4*)(src + 4);
    s16x8 o;
    o[0] = (short)f2bf(a.x); o[1] = (short)f2bf(a.y);
    o[2] = (short)f2bf(a.z); o[3] = (short)f2bf(a.w);
    o[4] = (short)f2bf(b.x); o[5] = (short)f2bf(b.y);
    o[6] = (short)f2bf(b.z); o[7] = (short)f2bf(b.w);
    *(s16x8*)(Wall + (size_t)i * 8) = o;
  }
  // wdecT[k][n] = wdec[n][k]
  for (int i = gid; i < 262144; i += stride) {
    int n = i >> 9, k = i & 511;
    wdecT[(size_t)k * 512 + n] = f2bf(wdec[i]);
  }
  // avgbf = bf16( sum(pavg[0..27]) / 196 )
  for (int i = gid; i < 16384; i += stride) {
    int b = i >> 8, e8 = (i & 255) * 8;
    float s[8] = {};
#pragma unroll 4
    for (int px = 0; px < 28; px++) {
      const float* pp = pavg + ((size_t)px * Bn + b) * ENCn + e8;
      float4 v0 = *(const float4*)pp, v1 = *(const float4*)(pp + 4);
      s[0] += v0.x; s[1] += v0.y; s[2] += v0.z; s[3] += v0.w;
      s[4] += v1.x; s[5] += v1.y; s[6] += v1.z; s[7] += v1.w;
    }
    s16x8 o;
#pragma unroll
    for (int j = 0; j < 8; j++) o[j] = (short)f2bf(s[j] * (1.f / 196.f));
    *(s16x8*)(avgbf + (size_t)b * ENCn + e8) = o;
  }
}

// ---------------- h0 + c0 + zero decpart[1..3] --------------------------------
__global__ __launch_bounds__(256) void k_h0c0(
    const u16* __restrict__ avgbf,
    const u16* __restrict__ h0wbf, const float* __restrict__ h0b,
    const u16* __restrict__ c0wbf, const float* __restrict__ c0b,
    u16* __restrict__ h0out, float* __restrict__ c0out,
    float* __restrict__ decpart) {
  int idx = blockIdx.x * 256 + threadIdx.x;   // 16384 threads
  float* dz = decpart + (size_t)Bn * 512;     // slices 1..3 = 98304 floats
#pragma unroll
  for (int j = 0; j < 6; j++) dz[(size_t)j * 16384 + idx] = 0.f;

  int wid = threadIdx.x >> 6, lane = threadIdx.x & 63;
  int r = lane & 15, hi = lane >> 4;
  bool isC = blockIdx.x >= 32;
  int n0 = ((int)blockIdx.x & 31) * 16;
  const u16* W = (isC ? c0wbf : h0wbf) + (size_t)(n0 + r) * ENCn + hi * 8;
  const u16* ap = avgbf + (size_t)(wid * 16 + r) * ENCn + hi * 8;
  f32x4 acc = {0.f, 0.f, 0.f, 0.f};
#pragma unroll 4
  for (int k = 0; k < ENCn; k += 32) acc = mfma(ld8(ap + k), ld8(W + k), acc);
  int col = n0 + r;
  float bb = (isC ? c0b : h0b)[col];
#pragma unroll
  for (int j = 0; j < 4; j++) {
    int row = wid * 16 + hi * 4 + j;
    float v = fmaxf(acc[j] + bb, 0.f);
    if (isC) c0out[(size_t)row * DECn + col] = v;
    else     h0out[(size_t)row * DECn + col] = f2bf(v);
  }
}

// ---------------- generic skinny GEMM (initial decpart[0]) --------------------
template<typename TA, typename TW, int K>
__global__ __launch_bounds__(256) void k_lin64(
    const TA* __restrict__ A, const TW* __restrict__ W,
    const float* __restrict__ bias1, float* __restrict__ outF, size_t ldo) {
  int wid = threadIdx.x >> 6, lane = threadIdx.x & 63;
  int r = lane & 15, hi = lane >> 4;
  int n0 = blockIdx.x * 16;
  const TA* ap = A + (size_t)(wid * 16 + r) * K + hi * 8;
  const TW* wp = W + (size_t)(n0 + r) * K + hi * 8;
  f32x4 acc = {0.f, 0.f, 0.f, 0.f};
  for (int k = 0; k < K; k += 32) acc = mfma(ld8(ap + k), ld8(wp + k), acc);
  int col = n0 + r;
  float bb = bias1 ? bias1[col] : 0.f;
#pragma unroll
  for (int j = 0; j < 4; j++) {
    int row = wid * 16 + hi * 4 + j;
    outF[(size_t)row * ldo + col] = acc[j] + bb;
  }
}

// ---------------- G projection: [12544,2048] = feat @ Wall[0:2048]^T ----------
// grid (16, 98) — R13 best-measured config (158us, MfmaUtil 28.8).
__global__ __launch_bounds__(256) void k_gproj(
    const u16* __restrict__ Abf, const u16* __restrict__ Wall,
    u16* __restrict__ G) {
  __shared__ u16 As[128][32];
  __shared__ u16 Bs[128][32];
  int tid = threadIdx.x;
  int wid = tid >> 6, lane = tid & 63, r = lane & 15, hi = lane >> 4;
  int wm = wid >> 1, wn = wid & 1;
  int m0 = blockIdx.y * 128, n0 = blockIdx.x * 128;
  int srow = tid >> 2, scol = (tid & 3) * 8;
  const u16* ga  = Abf  + (size_t)(m0 + srow) * ENCn + scol;
  const u16* gb1 = Wall + (size_t)(n0 + srow) * 2048 + scol;
  const u16* gb2 = Wall + (size_t)(n0 + 64 + srow) * 2048 + scol;
  u16* As1 = &As[0][0];
  u16* Bs1 = &Bs[0][0];
  f32x4 acc[4][4] = {};
  for (int k0 = 0; k0 < ENCn; k0 += 32) {
    GLOAD_LDS16(ga + k0,                      As1 + wid * 512);
    GLOAD_LDS16(ga + k0 + (size_t)64 * ENCn,  As1 + 2048 + wid * 512);
    GLOAD_LDS16(gb1 + k0,                     Bs1 + wid * 512);
    GLOAD_LDS16(gb2 + k0,                     Bs1 + 2048 + wid * 512);
    __syncthreads();
    s16x8 af[4], bfr[4];
#pragma unroll
    for (int i = 0; i < 4; i++) af[i]  = *(const s16x8*)(As1 + (wm * 64 + i * 16 + r) * 32 + hi * 8);
#pragma unroll
    for (int j = 0; j < 4; j++) bfr[j] = *(const s16x8*)(Bs1 + (wn * 64 + j * 16 + r) * 32 + hi * 8);
#pragma unroll
    for (int i = 0; i < 4; i++)
#pragma unroll
      for (int j = 0; j < 4; j++)
        acc[i][j] = mfma(af[i], bfr[j], acc[i][j]);
    __syncthreads();
  }
#pragma unroll
  for (int i = 0; i < 4; i++)
#pragma unroll
    for (int j = 0; j < 4; j++) {
      int col = n0 + wn * 64 + j * 16 + r;
#pragma unroll
      for (int q = 0; q < 4; q++) {
        int row = m0 + wm * 64 + i * 16 + hi * 4 + q;
        G[(size_t)row * 2048 + col] = f2bf(acc[i][j][q]);
      }
    }
}

// ---------------- enc projection: [12544,512] = feat @ Wall[2048:]^T + b ------
// 1D grid 392 = 8 x 49, XCD chunk swizzle (R16, neutral-to-positive).
__global__ __launch_bounds__(256) void k_encproj(
    const u16* __restrict__ Abf, const u16* __restrict__ Wall,
    const float* __restrict__ encb, u16* __restrict__ encp) {
  __shared__ u16 As[128][32];
  __shared__ u16 Bs[128][32];
  int lid = blockIdx.x;
  int w = (lid & 7) * 49 + (lid >> 3);    // bijective (392 % 8 == 0)
  int bx = w & 3, by = w >> 2;
  int tid = threadIdx.x;
  int wid = tid >> 6, lane = tid & 63, r = lane & 15, hi = lane >> 4;
  int wm = wid >> 1, wn = wid & 1;
  int m0 = by * 128, n0 = bx * 128;
  int srow = tid >> 2, scol = (tid & 3) * 8;
  const u16* ga  = Abf  + (size_t)(m0 + srow) * ENCn + scol;
  const u16* gb1 = Wall + (size_t)(2048 + n0 + srow) * 2048 + scol;
  const u16* gb2 = Wall + (size_t)(2048 + n0 + 64 + srow) * 2048 + scol;
  u16* As1 = &As[0][0];
  u16* Bs1 = &Bs[0][0];
  f32x4 acc[4][4] = {};
  for (int k0 = 0; k0 < ENCn; k0 += 32) {
    GLOAD_LDS16(ga + k0,                      As1 + wid * 512);
    GLOAD_LDS16(ga + k0 + (size_t)64 * ENCn,  As1 + 2048 + wid * 512);
    GLOAD_LDS16(gb1 + k0,                     Bs1 + wid * 512);
    GLOAD_LDS16(gb2 + k0,                     Bs1 + 2048 + wid * 512);
    __syncthreads();
    s16x8 af[4], bfr[4];
#pragma unroll
    for (int i = 0; i < 4; i++) af[i]  = *(const s16x8*)(As1 + (wm * 64 + i * 16 + r) * 32 + hi * 8);
#pragma unroll
    for (int j = 0; j < 4; j++) bfr[j] = *(const s16x8*)(Bs1 + (wn * 64 + j * 16 + r) * 32 + hi * 8);
#pragma unroll
    for (int i = 0; i < 4; i++)
#pragma unroll
      for (int j = 0; j < 4; j++)
        acc[i][j] = mfma(af[i], bfr[j], acc[i][j]);
    __syncthreads();
  }
#pragma unroll
  for (int i = 0; i < 4; i++)
#pragma unroll
    for (int j = 0; j < 4; j++) {
      int col = n0 + wn * 64 + j * 16 + r;
      float bb = encb[col];
#pragma unroll
      for (int q = 0; q < 4; q++) {
        int row = m0 + wm * 64 + i * 16 + hi * 4 + q;
        encp[(size_t)row * 512 + col] = f2bf(acc[i][j][q] + bb);
      }
    }
}

// ---------------- E = emb(caps) @ Wemb^T for ALL steps: [1280,2048], K=512 ----
__global__ __launch_bounds__(256) void k_eproj(
    const u16* __restrict__ embbf, const int* __restrict__ caps,
    const u16* __restrict__ Wemb, float* __restrict__ E) {
  __shared__ u16 As[128][32];
  __shared__ u16 Bs[128][32];
  int tid = threadIdx.x;
  int wid = tid >> 6, lane = tid & 63, r = lane & 15, hi = lane >> 4;
  int wm = wid >> 1, wn = wid & 1;
  int m0 = blockIdx.y * 128, n0 = blockIdx.x * 128;
  int srow = tid >> 2, scol = (tid & 3) * 8;
  int row1 = m0 + srow, row2 = row1 + 64;
  int id1 = caps[(row1 & 63) * Sn + (row1 >> 6)];
  int id2 = caps[(row2 & 63) * Sn + (row2 >> 6)];
  const u16* ga1 = embbf + (size_t)id1 * 512 + scol;
  const u16* ga2 = embbf + (size_t)id2 * 512 + scol;
  const u16* gb1 = Wemb + (size_t)(n0 + srow) * 512 + scol;
  const u16* gb2 = Wemb + (size_t)(n0 + 64 + srow) * 512 + scol;
  u16* As1 = &As[0][0];
  u16* Bs1 = &Bs[0][0];
  f32x4 acc[4][4] = {};
  for (int k0 = 0; k0 < 512; k0 += 32) {
    GLOAD_LDS16(ga1 + k0, As1 + wid * 512);
    GLOAD_LDS16(ga2 + k0, As1 + 2048 + wid * 512);
    GLOAD_LDS16(gb1 + k0, Bs1 + wid * 512);
    GLOAD_LDS16(gb2 + k0, Bs1 + 2048 + wid * 512);
    __syncthreads();
    s16x8 af[4], bfr[4];
#pragma unroll
    for (int i = 0; i < 4; i++) af[i]  = *(const s16x8*)(As1 + (wm * 64 + i * 16 + r) * 32 + hi * 8);
#pragma unroll
    for (int j = 0; j < 4; j++) bfr[j] = *(const s16x8*)(Bs1 + (wn * 64 + j * 16 + r) * 32 + hi * 8);
#pragma unroll
    for (int i = 0; i < 4; i++)
#pragma unroll
      for (int j = 0; j < 4; j++)
        acc[i][j] = mfma(af[i], bfr[j], acc[i][j]);
    __syncthreads();
  }
#pragma unroll
  for (int i = 0; i < 4; i++)
#pragma unroll
    for (int j = 0; j < 4; j++) {
      int col = n0 + wn * 64 + j * 16 + r;
#pragma unroll
      for (int q = 0; q < 4; q++) {
        int row = m0 + wm * 64 + i * 16 + hi * 4 + q;
        E[(size_t)row * 2048 + col] = acc[i][j][q];
      }
    }
}

// ---------------- STEP K1: attn (decp from partials) + h@Whh slices -----------
__global__ __launch_bounds__(256) void k_step1(
    const u16* __restrict__ encp, const float* __restrict__ decpart,
    const float* __restrict__ wdecb,
    const float* __restrict__ Vw, const float* __restrict__ Vb,
    float* __restrict__ e_s,
    const u16* __restrict__ hin, const u16* __restrict__ Whh,
    float* __restrict__ p2) {
  int bx = blockIdx.x, by = blockIdx.y;
  int wid = threadIdx.x >> 6, lane = threadIdx.x & 63;
  if (bx < 49) {
    int p = bx * 4 + wid, b = by;
    int cb = lane * 8;
    float4 dv0 = *(const float4*)(wdecb + cb);
    float4 dv1 = *(const float4*)(wdecb + cb + 4);
#pragma unroll
    for (int q = 0; q < 4; q++) {
      const float* dq = decpart + ((size_t)q * Bn + b) * 512 + cb;
      float4 v0 = *(const float4*)dq, v1 = *(const float4*)(dq + 4);
      dv0.x += v0.x; dv0.y += v0.y; dv0.z += v0.z; dv0.w += v0.w;
      dv1.x += v1.x; dv1.y += v1.y; dv1.z += v1.z; dv1.w += v1.w;
    }
    float4 vv0 = *(const float4*)(Vw + cb), vv1 = *(const float4*)(Vw + cb + 4);
    s16x8 ev = *(const s16x8*)(encp + (((size_t)(b * Pn + p)) << 9) + cb);
    float s = 0.f;
    s += vv0.x * tanh_fast(bf2f((u16)ev[0]) + dv0.x);
    s += vv0.y * tanh_fast(bf2f((u16)ev[1]) + dv0.y);
    s += vv0.z * tanh_fast(bf2f((u16)ev[2]) + dv0.z);
    s += vv0.w * tanh_fast(bf2f((u16)ev[3]) + dv0.w);
    s += vv1.x * tanh_fast(bf2f((u16)ev[4]) + dv1.x);
    s += vv1.y * tanh_fast(bf2f((u16)ev[5]) + dv1.y);
    s += vv1.z * tanh_fast(bf2f((u16)ev[6]) + dv1.z);
    s += vv1.w * tanh_fast(bf2f((u16)ev[7]) + dv1.w);
    for (int m = 32; m; m >>= 1) s += __shfl_xor(s, m);
    if (lane == 0) e_s[(size_t)b * Pn + p] = s + Vb[0];
  } else {
    int sb = (bx - 49) * 64 + by;          // 0..127
    int n0 = sb * 16;
    int r = lane & 15, hi = lane >> 4;
    int brow = wid * 16 + r;
    f32x4 acc = {0.f, 0.f, 0.f, 0.f};
    const u16* a2 = hin + (size_t)brow * DECn + hi * 8;
    const u16* w2 = Whh + (size_t)(n0 + r) * 512 + hi * 8;
#pragma unroll 4
    for (int k = 0; k < 512; k += 32) acc = mfma(ld8(a2 + k), ld8(w2 + k), acc);
#pragma unroll
    for (int j = 0; j < 4; j++) {
      int row = wid * 16 + hi * 4 + j;
      p2[(size_t)row * 2048 + n0 + r] = acc[j];
    }
  }
}

// ---------------- STEP K2: softmax + G-sum + LSTM + decp partials, 512 thr ----
__global__ __launch_bounds__(512) void k_step2(
    const float* __restrict__ e_s, const u16* __restrict__ G,
    const float* __restrict__ p2, const float* __restrict__ Et,
    const float* __restrict__ bih, const float* __restrict__ bhh,
    float* __restrict__ cbuf, u16* __restrict__ hnew,
    const u16* __restrict__ wdecT, float* __restrict__ decpart) {
  __shared__ float sw[Pn];
  __shared__ float red[512];
  __shared__ float pacc[8 * 512];
  __shared__ float hsh[128];
  int b = blockIdx.y, c = blockIdx.x, tid = threadIdx.x;
  // softmax over 196
  float ev = (tid < Pn) ? e_s[(size_t)b * Pn + tid] : -3.0e38f;
  red[tid] = ev; __syncthreads();
  for (int s = 256; s > 0; s >>= 1) { if (tid < s) red[tid] = fmaxf(red[tid], red[tid + s]); __syncthreads(); }
  float m = red[0]; __syncthreads();
  float ex = (tid < Pn) ? __expf(ev - m) : 0.f;
  red[tid] = ex; __syncthreads();
  for (int s = 256; s > 0; s >>= 1) { if (tid < s) red[tid] += red[tid + s]; __syncthreads(); }
  float inv = 1.f / red[0];
  if (tid < Pn) sw[tid] = ex * inv;
  __syncthreads();
  // weighted sum: 8 p-groups x 64 threads; thread owns 8 cols
  int g = tid >> 6, t64 = tid & 63;
  int dloc = t64 * 8;
  const u16* gp = G + (size_t)b * Pn * 2048 + c * 512 + dloc;
  float acc[8] = {};
#pragma unroll 2
  for (int p = g; p < Pn; p += 8) {
    float w = sw[p];
    s16x8 v = *(const s16x8*)(gp + (size_t)p * 2048);
#pragma unroll
    for (int j = 0; j < 8; j++) acc[j] += w * bf2f((u16)v[j]);
  }
#pragma unroll
  for (int j = 0; j < 8; j++) pacc[g * 512 + j * 64 + t64] = acc[j];
  __syncthreads();
  // LSTM pointwise for 128 dims (G cols interleaved lc = d_local*4+g)
  if (tid < 128) {
    int d = c * 128 + tid;
    float gv[4];
#pragma unroll
    for (int gg = 0; gg < 4; gg++) {
      int lc = tid * 4 + gg;
      int ia = (lc & 7) * 64 + (lc >> 3);
      float s = 0.f;
#pragma unroll
      for (int gr = 0; gr < 8; gr++) s += pacc[gr * 512 + ia];
      int col = gg * 512 + d;
      gv[gg] = s + p2[(size_t)b * 2048 + col] + Et[(size_t)b * 2048 + col]
             + bih[col] + bhh[col];
    }
    size_t ci = (size_t)b * DECn + d;
    float cn = sigm(gv[1]) * cbuf[ci] + sigm(gv[0]) * tanh_fast(gv[2]);
    float hn = sigm(gv[3]) * tanh_fast(cn);
    cbuf[ci] = cn;
    hnew[ci] = f2bf(hn);
    hsh[tid] = hn;
  }
  __syncthreads();
  // decp partial: this block's 128 h dims x 512 cols; thread owns 1 col
  float a0 = 0.f;
#pragma unroll 8
  for (int k = 0; k < 128; k++)
    a0 += hsh[k] * bf2f(wdecT[(size_t)(c * 128 + k) * 512 + tid]);
  decpart[((size_t)c * Bn + b) * 512 + tid] = a0;
}

// ---------------- deferred logits GEMM, bijective XCD swizzle (n-major) -------
__global__ __launch_bounds__(256) void k_logits(
    const u16* __restrict__ hA, const u16* __restrict__ Wbf,
    const float* __restrict__ bias, float* __restrict__ out) {
  __shared__ u16 As[128][32];
  __shared__ u16 Bs[128][32];
  int lid = blockIdx.x;
  int xcd = lid & 7, idx = lid >> 3;
  int w = (xcd < 6) ? xcd * 99 + idx : 6 * 99 + (xcd - 6) * 98 + idx;
  int bx = w / 10, by = w % 10;   // n-major: W slice L2-resident per XCD
  int tid = threadIdx.x;
  int wid = tid >> 6, lane = tid & 63, r = lane & 15, hi = lane >> 4;
  int wm = wid >> 1, wn = wid & 1;
  int m0 = by * 128, n0 = bx * 128;
  int srow = tid >> 2, scol = (tid & 3) * 8;
  const u16* ga = hA + (size_t)(m0 + srow) * 512 + scol;
  int br1 = n0 + srow;       if (br1 > VOCABn - 1) br1 = VOCABn - 1;
  int br2 = n0 + 64 + srow;  if (br2 > VOCABn - 1) br2 = VOCABn - 1;
  const u16* gb1 = Wbf + (size_t)br1 * 512 + scol;
  const u16* gb2 = Wbf + (size_t)br2 * 512 + scol;
  u16* As1 = &As[0][0];
  u16* Bs1 = &Bs[0][0];
  f32x4 acc[4][4] = {};
  for (int k0 = 0; k0 < 512; k0 += 32) {
    GLOAD_LDS16(ga + k0,                     As1 + wid * 512);
    GLOAD_LDS16(ga + k0 + (size_t)64 * 512,  As1 + 2048 + wid * 512);
    GLOAD_LDS16(gb1 + k0,                    Bs1 + wid * 512);
    GLOAD_LDS16(gb2 + k0,                    Bs1 + 2048 + wid * 512);
    __syncthreads();
    s16x8 af[4], bfr[4];
#pragma unroll
    for (int i = 0; i < 4; i++) af[i]  = *(const s16x8*)(As1 + (wm * 64 + i * 16 + r) * 32 + hi * 8);
#pragma unroll
    for (int j = 0; j < 4; j++) bfr[j] = *(const s16x8*)(Bs1 + (wn * 64 + j * 16 + r) * 32 + hi * 8);
#pragma unroll
    for (int i = 0; i < 4; i++)
#pragma unroll
      for (int j = 0; j < 4; j++)
        acc[i][j] = mfma(af[i], bfr[j], acc[i][j]);
    __syncthreads();
  }
#pragma unroll
  for (int i = 0; i < 4; i++)
#pragma unroll
    for (int j = 0; j < 4; j++) {
      int col = n0 + wn * 64 + j * 16 + r;
      if (col < VOCABn) {
        float bb = bias[col];
#pragma unroll
        for (int q = 0; q < 4; q++) {
          int row = m0 + wm * 64 + i * 16 + hi * 4 + q;   // row = t*64 + b
          int tt = row >> 6, b = row & 63;
          out[((size_t)b * Sn + tt) * VOCABn + col] = acc[i][j][q] + bb;
        }
      }
    }
}

// ============================================================================
extern "C" void kernel_launch(void* const* d_in, const int* in_sizes, int n_in,
                              void* d_out, int out_size, void* d_ws, size_t ws_size,
                              hipStream_t stream) {
  const float* image_feat = (const float*)d_in[0];
  const int*   captions   = (const int*)d_in[1];
  const float* wenc_w = (const float*)d_in[2];
  const float* wenc_b = (const float*)d_in[3];
  const float* wdec_w = (const float*)d_in[4];
  const float* wdec_b = (const float*)d_in[5];
  const float* V_w    = (const float*)d_in[6];
  const float* V_b    = (const float*)d_in[7];
  const float* embed_w = (const float*)d_in[8];
  const float* h0_w = (const float*)d_in[9];
  const float* h0_b = (const float*)d_in[10];
  const float* c0_w = (const float*)d_in[11];
  const float* c0_b = (const float*)d_in[12];
  const float* W_ih = (const float*)d_in[13];
  const float* b_ih = (const float*)d_in[14];
  const float* W_hh = (const float*)d_in[15];
  const float* b_hh = (const float*)d_in[16];
  const float* fc_w = (const float*)d_in[17];
  const float* fc_b = (const float*)d_in[18];
  float* out = (float*)d_out;

  char* w = (char*)d_ws;
  auto alloc = [&](size_t bytes) { void* p = (void*)w; w += (bytes + 255) & ~(size_t)255; return p; };
  u16* if_bf   = (u16*)alloc(sizeof(u16) * (size_t)Bn * Pn * ENCn);
  u16* Gbuf    = (u16*)alloc(sizeof(u16) * (size_t)Bn * Pn * 2048);
  u16* encp    = (u16*)alloc(sizeof(u16) * (size_t)Bn * Pn * ATTn);
  u16* Wall    = (u16*)alloc(sizeof(u16) * (size_t)2560 * 2048);
  u16* wdec_bf = (u16*)alloc(sizeof(u16) * (size_t)ATTn * DECn);
  u16* wdecT   = (u16*)alloc(sizeof(u16) * (size_t)DECn * DECn);
  u16* Wemb    = (u16*)alloc(sizeof(u16) * (size_t)2048 * 512);
  u16* Whh_bf  = (u16*)alloc(sizeof(u16) * (size_t)2048 * 512);
  u16* fcw_bf  = (u16*)alloc(sizeof(u16) * (size_t)VOCABn * DECn);
  u16* emb_bf  = (u16*)alloc(sizeof(u16) * (size_t)VOCABn * EMBn);
  u16* h0w_bf  = (u16*)alloc(sizeof(u16) * (size_t)DECn * ENCn);
  u16* c0w_bf  = (u16*)alloc(sizeof(u16) * (size_t)DECn * ENCn);
  u16* avg_bf  = (u16*)alloc(sizeof(u16) * (size_t)Bn * ENCn);
  u16* hall    = (u16*)alloc(sizeof(u16) * (size_t)(Sn + 1) * Bn * DECn);
  float* Ebuf  = (float*)alloc(sizeof(float) * (size_t)Sn * Bn * 2048);
  float* pavg  = (float*)alloc(sizeof(float) * (size_t)28 * Bn * ENCn);
  float* e_s   = (float*)alloc(sizeof(float) * (size_t)Bn * Pn);
  float* cbuf  = (float*)alloc(sizeof(float) * (size_t)Bn * DECn);
  float* p2    = (float*)alloc(sizeof(float) * (size_t)Bn * 2048);
  float* decpart = (float*)alloc(sizeof(float) * (size_t)4 * Bn * 512);

  // one-time prep
  k_cvtfeat_part<<<dim3(28, Bn), 256, 0, stream>>>(image_feat, if_bf, pavg);
  k_cvt_all<<<2048, 256, 0, stream>>>(wenc_w, wdec_w, wdec_bf,
                                      W_ih, Wemb, W_hh, Whh_bf,
                                      fc_w, fcw_bf, embed_w, emb_bf,
                                      h0_w, h0w_bf, c0_w, c0w_bf,
                                      Wall, wdecT, pavg, avg_bf);
  k_gproj<<<dim3(16, 98), 256, 0, stream>>>(if_bf, Wall, Gbuf);
  k_encproj<<<392, 256, 0, stream>>>(if_bf, Wall, wenc_b, encp);
  k_eproj<<<dim3(16, 10), 256, 0, stream>>>(emb_bf, captions, Wemb, Ebuf);
  k_h0c0<<<64, 256, 0, stream>>>(avg_bf, h0w_bf, h0_b, c0w_bf, c0_b,
                                 hall, cbuf, decpart);
  k_lin64<u16, u16, 512><<<32, 256, 0, stream>>>(hall, wdec_bf, nullptr, decpart, 512);

  for (int t = 0; t < Sn; t++) {
    const u16* hin = hall + (size_t)t * Bn * DECn;
    u16* hnew = hall + (size_t)(t + 1) * Bn * DECn;
    k_step1<<<dim3(51, Bn), 256, 0, stream>>>(encp, decpart, wdec_b, V_w, V_b, e_s,
                                              hin, Whh_bf, p2);
    k_step2<<<dim3(4, Bn), 512, 0, stream>>>(e_s, Gbuf, p2,
                                             Ebuf + (size_t)t * Bn * 2048,
                                             b_ih, b_hh, cbuf, hnew, wdecT, decpart);
  }
  k_logits<<<790, 256, 0, stream>>>(hall + (size_t)Bn * DECn, fcw_bf, fc_b, out);
}